// Round 1
// baseline (3601.180 us; speedup 1.0000x reference)
//
#include <hip/hip_runtime.h>

#define GN   128      // graphs
#define GP   256      // nodes per graph
#define NN   32768    // total nodes
#define NEDGE 262144  // total edges
#define WALKN 20

// ============================================================
// RWSE: build A (dense counts) + edge dst-CSR
// ============================================================
__global__ __launch_bounds__(256) void build_edges(const int* __restrict__ ei, float* __restrict__ A,
                                                   int* __restrict__ Ecsr, int* __restrict__ Ecnt){
  int e = blockIdx.x*256 + threadIdx.x;
  int s = ei[e], d = ei[NEDGE + e];
  int g = s >> 8;
  atomicAdd(&A[((size_t)g<<16) + ((size_t)(s&255)<<8) + (size_t)(d&255)], 1.0f);
  int pos = atomicAdd(&Ecnt[d], 1);
  if (pos < 64) Ecsr[((size_t)d<<6) + pos] = e;
}

// add self loops + out-degree (row sums, clipped >=1)
__global__ __launch_bounds__(256) void rwse_deg(float* __restrict__ A, float* __restrict__ deg){
  int g = blockIdx.x, r = threadIdx.x;
  float* row = A + ((size_t)g<<16) + ((size_t)r<<8);
  row[r] += 1.0f;
  float s = 0.f;
  for (int c = 0; c < 256; c += 4){
    float4 v = *(const float4*)&row[c];
    s += v.x + v.y + v.z + v.w;
  }
  deg[(g<<8)+r] = fmaxf(s, 1.0f);
}

// M[c][r] = A[r][c]/deg[r]; padded CSR over nonzeros of each M-row c
__global__ __launch_bounds__(256) void rwse_csr(const float* __restrict__ A, const float* __restrict__ deg,
                                                int* __restrict__ Midx, float* __restrict__ Mw,
                                                int* __restrict__ Mcnt){
  int g = blockIdx.x, c = threadIdx.x;
  __shared__ float degs[256];
  degs[c] = deg[(g<<8)+c];
  __syncthreads();
  const float* Ag = A + ((size_t)g<<16);
  size_t base = ((size_t)((g<<8)+c)) << 6;
  int cnt = 0;
  for (int r = 0; r < 256; r++){
    float a = Ag[((size_t)r<<8)+c];
    if (a > 0.f && cnt < 64){
      Midx[base+cnt] = r;
      Mw[base+cnt]   = a / degs[r];
      cnt++;
    }
  }
  Mcnt[(g<<8)+c] = cnt;
}

__global__ __launch_bounds__(256) void p0_init(float* __restrict__ P0){
  size_t idx = (size_t)blockIdx.x*256 + threadIdx.x;   // 8,388,608 total
  int rc = (int)(idx & 65535);
  P0[idx] = ((rc>>8) == (rc&255)) ? 1.f : 0.f;
}

// one sparse power step: Pout[c, cb..cb+63] = sum_r M[c,r]*Pin[r, cb..cb+63]; record diag
__global__ __launch_bounds__(256) void rwse_step(const float* __restrict__ Pin, float* __restrict__ Pout,
                                                 const int* __restrict__ Midx, const float* __restrict__ Mw,
                                                 const int* __restrict__ Mcnt, float* __restrict__ pe, int step){
  __shared__ __align__(16) float Ps[256][64];   // 64KB: column-slice of Pin
  int g  = blockIdx.x >> 2;
  int cb = (blockIdx.x & 3) * 64;
  int tid = threadIdx.x;
  const float* Pg = Pin + ((size_t)g << 16);
  // stage Pin[:, cb..cb+63]
  #pragma unroll
  for (int t = 0; t < 16; t++){
    int idx4 = tid + t*256;            // float4 index over 4096
    int rr = idx4 >> 4, c4 = (idx4 & 15) << 2;
    *(float4*)&Ps[rr][c4] = *(const float4*)&Pg[((size_t)rr<<8) + cb + c4];
  }
  __syncthreads();
  int wave = tid >> 6, ln = tid & 63;
  float* Pog = Pout + ((size_t)g << 16);
  for (int c = wave*64; c < wave*64 + 64; c++){
    int nc = (g<<8) + c;
    int cnt = Mcnt[nc];
    const int*   idx = Midx + ((size_t)nc << 6);
    const float* w   = Mw   + ((size_t)nc << 6);
    float acc = 0.f;
    for (int j = 0; j < cnt; j++){
      acc += w[j] * Ps[idx[j]][ln];
    }
    Pog[((size_t)c<<8) + cb + ln] = acc;
    if (cb + ln == c) pe[(size_t)nc * WALKN + step] = acc;
  }
}

// ============================================================
// concat [x | pe] -> xin [N,50]
// ============================================================
__global__ __launch_bounds__(256) void concat_kernel(const float* __restrict__ x, const float* __restrict__ pe,
                                                     float* __restrict__ xin){
  int idx = blockIdx.x*256 + threadIdx.x;
  if (idx >= NN*50) return;
  int row = idx / 50, c = idx % 50;
  xin[idx] = (c < 30) ? x[(size_t)row*30 + c] : pe[(size_t)row*20 + (c-30)];
}

// ============================================================
// Generic fused GEMM: Y = [BN]( [relu]( (X1[+X2]) @ W + b ) [+R] ) [+R2]
//   64-row x 128-col tile, k-tile 64, fp32
// ============================================================
template<int CIN, bool RELU, bool BN, bool HAS_X2, bool HAS_R, bool HAS_R2>
__global__ __launch_bounds__(256, 2) void gemm_fused(
    const float* __restrict__ X1, const float* __restrict__ X2,
    const float* __restrict__ W, const float* __restrict__ bias,
    const float* __restrict__ Rp, const float* __restrict__ R2p,
    const float* __restrict__ bng, const float* __restrict__ bnb,
    const float* __restrict__ bnm, const float* __restrict__ bnv,
    float* __restrict__ Y, int ldY, int colTiles)
{
  __shared__ __align__(16) float Wt[64][128];    // 32KB
  __shared__ __align__(16) float XtT[64][68];    // 17.4KB, transposed, padded
  int bt = blockIdx.x;
  int row0 = (bt / colTiles) * 64;
  int c0   = (bt % colTiles) * 128;
  int tid = threadIdx.x;
  int cq = tid & 15, rg = tid >> 4;
  int c8 = cq * 8;
  float acc[4][8];
  #pragma unroll
  for (int j = 0; j < 4; j++)
    #pragma unroll
    for (int cc = 0; cc < 8; cc++) acc[j][cc] = 0.f;

  for (int k0 = 0; k0 < CIN; k0 += 64){
    #pragma unroll 8
    for (int t = 0; t < 32; t++){        // Wt: 8192 elems
      int idx = tid + t*256;
      int kk = idx >> 7, cc = idx & 127;
      float v = 0.f;
      if (k0 + kk < CIN) v = W[(size_t)(k0+kk)*ldY + c0 + cc];
      Wt[kk][cc] = v;
    }
    #pragma unroll 8
    for (int t = 0; t < 16; t++){        // XtT: 4096 elems (stored transposed)
      int idx = tid + t*256;
      int rr = idx >> 6, kk = idx & 63;
      float v = 0.f;
      if (k0 + kk < CIN){
        size_t off = (size_t)(row0+rr)*CIN + k0 + kk;
        v = X1[off];
        if (HAS_X2) v += X2[off];
      }
      XtT[kk][rr] = v;
    }
    __syncthreads();
    #pragma unroll 8
    for (int k = 0; k < 64; k++){
      float4 xv = *(const float4*)&XtT[k][rg*4];
      float4 w0 = *(const float4*)&Wt[k][c8];
      float4 w1 = *(const float4*)&Wt[k][c8+4];
      acc[0][0] += xv.x*w0.x; acc[0][1] += xv.x*w0.y; acc[0][2] += xv.x*w0.z; acc[0][3] += xv.x*w0.w;
      acc[0][4] += xv.x*w1.x; acc[0][5] += xv.x*w1.y; acc[0][6] += xv.x*w1.z; acc[0][7] += xv.x*w1.w;
      acc[1][0] += xv.y*w0.x; acc[1][1] += xv.y*w0.y; acc[1][2] += xv.y*w0.z; acc[1][3] += xv.y*w0.w;
      acc[1][4] += xv.y*w1.x; acc[1][5] += xv.y*w1.y; acc[1][6] += xv.y*w1.z; acc[1][7] += xv.y*w1.w;
      acc[2][0] += xv.z*w0.x; acc[2][1] += xv.z*w0.y; acc[2][2] += xv.z*w0.z; acc[2][3] += xv.z*w0.w;
      acc[2][4] += xv.z*w1.x; acc[2][5] += xv.z*w1.y; acc[2][6] += xv.z*w1.z; acc[2][7] += xv.z*w1.w;
      acc[3][0] += xv.w*w0.x; acc[3][1] += xv.w*w0.y; acc[3][2] += xv.w*w0.z; acc[3][3] += xv.w*w0.w;
      acc[3][4] += xv.w*w1.x; acc[3][5] += xv.w*w1.y; acc[3][6] += xv.w*w1.z; acc[3][7] += xv.w*w1.w;
    }
    __syncthreads();
  }
  #pragma unroll
  for (int j = 0; j < 4; j++){
    int r = row0 + rg*4 + j;
    #pragma unroll
    for (int cc = 0; cc < 8; cc++){
      int col = c0 + c8 + cc;
      float v = acc[j][cc] + bias[col];
      if (RELU) v = fmaxf(v, 0.f);
      if (HAS_R) v += Rp[(size_t)r*ldY + col];
      if (BN)   v = (v - bnm[col]) * rsqrtf(bnv[col] + 1e-5f) * bng[col] + bnb[col];
      if (HAS_R2) v += R2p[(size_t)r*ldY + col];
      Y[(size_t)r*ldY + col] = v;
    }
  }
}

// ============================================================
// per-layer collapsed edge weights: Wp = ep_W @ ge_W[i], bp = ep_b @ ge_W[i] + ge_b[i]
// ============================================================
__global__ __launch_bounds__(256) void wp_all(const float* __restrict__ epW, const float* __restrict__ epb,
                                              const float* __restrict__ geW, const float* __restrict__ geb,
                                              float* __restrict__ Wp, float* __restrict__ bp){
  int i = blockIdx.x;
  const float* gw = geW + (size_t)i*16384;
  float* wp = Wp + (size_t)i*1408;
  int tid = threadIdx.x;
  for (int idx = tid; idx < 1408; idx += 256){
    int t = idx >> 7, c = idx & 127;
    float s = 0.f;
    for (int k = 0; k < 128; k++) s += epW[t*128+k] * gw[(size_t)k*128 + c];
    wp[idx] = s;
  }
  if (tid < 128){
    float s = geb[(size_t)i*128 + tid];
    for (int k = 0; k < 128; k++) s += epb[k] * gw[(size_t)k*128 + tid];
    bp[(size_t)i*128 + tid] = s;
  }
}

// ============================================================
// GINE aggregation (no atomics, dst-CSR): aggr[n] = sum_e relu(h[src]+edge_attr[e]@Wp+bp)
// ============================================================
__global__ __launch_bounds__(256) void gine_aggr(const float* __restrict__ h, const float* __restrict__ ea,
                                                 const int* __restrict__ ei, const int* __restrict__ Ecsr,
                                                 const int* __restrict__ Ecnt,
                                                 const float* __restrict__ Wp, const float* __restrict__ bp,
                                                 float* __restrict__ aggr){
  int n = blockIdx.x*2 + (threadIdx.x >> 7);
  int ch = threadIdx.x & 127;
  int cnt = Ecnt[n]; if (cnt > 64) cnt = 64;
  float wreg[11];
  #pragma unroll
  for (int t = 0; t < 11; t++) wreg[t] = Wp[t*128 + ch];
  float bpc = bp[ch];
  float acc = 0.f;
  for (int j = 0; j < cnt; j++){
    int e = Ecsr[((size_t)n<<6) + j];
    int s = ei[e];
    const float* eap = ea + (size_t)e*11;
    float v = bpc;
    #pragma unroll
    for (int t = 0; t < 11; t++) v += eap[t] * wreg[t];
    v += h[(size_t)s*128 + ch];
    acc += fmaxf(v, 0.f);
  }
  aggr[(size_t)n*128 + ch] = acc;
}

// ============================================================
// attention: one block per (graph, head), flash-style, 1 query row / thread
// ============================================================
__global__ __launch_bounds__(256) void attn_kernel(const float* __restrict__ qkv, float* __restrict__ o){
  __shared__ __align__(16) float Ks[256*32];   // 32KB
  __shared__ __align__(16) float Vs[256*32];   // 32KB
  int g = blockIdx.x >> 2, hh = blockIdx.x & 3;
  int tid = threadIdx.x;
  #pragma unroll
  for (int t = 0; t < 8; t++){
    int idx = tid + t*256;               // float4 index over 2048
    int row = idx >> 3, d4 = idx & 7;
    size_t rb = (size_t)((g<<8)+row)*384;
    ((float4*)Ks)[idx] = *(const float4*)(qkv + rb + 128 + hh*32 + d4*4);
    ((float4*)Vs)[idx] = *(const float4*)(qkv + rb + 256 + hh*32 + d4*4);
  }
  float q[32];
  {
    const float4* qr = (const float4*)(qkv + (size_t)((g<<8)+tid)*384 + hh*32);
    #pragma unroll
    for (int d4 = 0; d4 < 8; d4++){
      float4 t = qr[d4];
      q[d4*4]=t.x; q[d4*4+1]=t.y; q[d4*4+2]=t.z; q[d4*4+3]=t.w;
    }
  }
  __syncthreads();
  float m = -1e30f, l = 0.f;
  float accv[32];
  #pragma unroll
  for (int d = 0; d < 32; d++) accv[d] = 0.f;
  for (int j = 0; j < 256; j++){
    float s = 0.f;
    #pragma unroll
    for (int d4 = 0; d4 < 8; d4++){
      float4 kv = ((const float4*)Ks)[j*8 + d4];
      s += q[d4*4]*kv.x + q[d4*4+1]*kv.y + q[d4*4+2]*kv.z + q[d4*4+3]*kv.w;
    }
    s *= 0.17677669529663687f;           // 32^-0.5
    float nm = fmaxf(m, s);
    float alpha = __expf(m - nm);
    float p = __expf(s - nm);
    l = l*alpha + p;
    #pragma unroll
    for (int d4 = 0; d4 < 8; d4++){
      float4 vv = ((const float4*)Vs)[j*8 + d4];
      accv[d4*4]   = accv[d4*4]  *alpha + p*vv.x;
      accv[d4*4+1] = accv[d4*4+1]*alpha + p*vv.y;
      accv[d4*4+2] = accv[d4*4+2]*alpha + p*vv.z;
      accv[d4*4+3] = accv[d4*4+3]*alpha + p*vv.w;
    }
    m = nm;
  }
  float inv = 1.f / l;
  float* orow = o + (size_t)((g<<8)+tid)*128 + hh*32;
  #pragma unroll
  for (int d4 = 0; d4 < 8; d4++){
    float4 t;
    t.x = accv[d4*4]*inv; t.y = accv[d4*4+1]*inv; t.z = accv[d4*4+2]*inv; t.w = accv[d4*4+3]*inv;
    *(float4*)(orow + d4*4) = t;
  }
}

// ============================================================
// mean-pool + 2-layer head
// ============================================================
__global__ __launch_bounds__(256) void head_kernel(const float* __restrict__ h,
                                                   const float* __restrict__ W1, const float* __restrict__ b1,
                                                   const float* __restrict__ W2, const float* __restrict__ b2,
                                                   float* __restrict__ out){
  int g = blockIdx.x, tid = threadIdx.x;
  int c = tid & 127, half = tid >> 7;
  __shared__ float part[2][128];
  __shared__ float pool[128];
  __shared__ float hid[64];
  float s = 0.f;
  for (int n = half*128; n < half*128 + 128; n++)
    s += h[(size_t)((g<<8)+n)*128 + c];
  part[half][c] = s;
  __syncthreads();
  if (tid < 128) pool[tid] = (part[0][tid] + part[1][tid]) * (1.f/256.f);
  __syncthreads();
  if (tid < 64){
    float v = b1[tid];
    for (int k = 0; k < 128; k++) v += pool[k] * W1[k*64 + tid];
    hid[tid] = fmaxf(v, 0.f);
  }
  __syncthreads();
  if (tid == 0){
    float v = b2[0];
    for (int k = 0; k < 64; k++) v += hid[k] * W2[k];
    out[g] = v;
  }
}

// ============================================================
extern "C" void kernel_launch(void* const* d_in, const int* in_sizes, int n_in,
                              void* d_out, int out_size, void* d_ws, size_t ws_size,
                              hipStream_t stream){
  (void)in_sizes; (void)n_in; (void)out_size; (void)ws_size;
  const float* x      = (const float*)d_in[0];
  const float* eattr  = (const float*)d_in[1];
  const float* in_W   = (const float*)d_in[2];
  const float* in_b   = (const float*)d_in[3];
  const float* ep_W   = (const float*)d_in[4];
  const float* ep_b   = (const float*)d_in[5];
  const float* ge_W   = (const float*)d_in[6];
  const float* ge_b   = (const float*)d_in[7];
  const float* g1_W   = (const float*)d_in[8];
  const float* g1_b   = (const float*)d_in[9];
  const float* g2_W   = (const float*)d_in[10];
  const float* g2_b   = (const float*)d_in[11];
  const float* qkv_W  = (const float*)d_in[12];
  const float* qkv_b  = (const float*)d_in[13];
  const float* o_W    = (const float*)d_in[14];
  const float* o_b    = (const float*)d_in[15];
  const float* bn1g = (const float*)d_in[16]; const float* bn1b = (const float*)d_in[17];
  const float* bn1m = (const float*)d_in[18]; const float* bn1v = (const float*)d_in[19];
  const float* bn2g = (const float*)d_in[20]; const float* bn2b = (const float*)d_in[21];
  const float* bn2m = (const float*)d_in[22]; const float* bn2v = (const float*)d_in[23];
  const float* bn3g = (const float*)d_in[24]; const float* bn3b = (const float*)d_in[25];
  const float* bn3m = (const float*)d_in[26]; const float* bn3v = (const float*)d_in[27];
  const float* m1_W = (const float*)d_in[28]; const float* m1_b = (const float*)d_in[29];
  const float* m2_W = (const float*)d_in[30]; const float* m2_b = (const float*)d_in[31];
  const float* h1_W = (const float*)d_in[32]; const float* h1_b = (const float*)d_in[33];
  const float* h2_W = (const float*)d_in[34]; const float* h2_b = (const float*)d_in[35];
  const int*   ei   = (const int*)d_in[36];
  float* out = (float*)d_out;
  float* ws  = (float*)d_ws;
  int*   wsi = (int*)d_ws;

  // ---- workspace layout (element offsets) ----
  const size_t oA    = 0;                        // 8,388,608 fp32
  const size_t oP0   = oA  + 8388608;
  const size_t oP1   = oP0 + 8388608;
  const size_t oMidx = oP1 + 8388608;            // 2,097,152 int
  const size_t oMw   = oMidx + 2097152;          // 2,097,152 fp32
  const size_t r0end = oMw + 2097152;            // 29,360,128
  // overlays on [0, r0end) once RWSE is done:
  const size_t oQKV  = 0;                        // 12,582,912
  const size_t oT2   = 12582912;                 // 8,388,608
  const size_t oOB   = 20971520;                 // 4,194,304
  const size_t oMcnt = r0end;                    // 32768 int
  const size_t oDeg  = oMcnt + 32768;
  const size_t oPe   = oDeg  + 32768;            // 655,360
  const size_t oXin  = oPe   + 655360;           // 1,638,400
  const size_t oH    = oXin  + 1638400;          // 4,194,304
  const size_t oAg   = oH    + 4194304;
  const size_t oT1   = oAg   + 4194304;
  const size_t oH1   = oT1   + 4194304;
  const size_t oOut  = oH1   + 4194304;
  const size_t oWp   = oOut  + 4194304;          // 4224
  const size_t oBp   = oWp   + 4224;             // 384
  const size_t oEcsr = oBp   + 384;              // 2,097,152 int
  const size_t oEcnt = oEcsr + 2097152;          // 32768 int

  // ---- RWSE ----
  hipMemsetAsync(ws + oA, 0, 8388608*sizeof(float), stream);
  hipMemsetAsync(wsi + oEcnt, 0, 32768*sizeof(int), stream);
  build_edges<<<NEDGE/256, 256, 0, stream>>>(ei, ws+oA, wsi+oEcsr, wsi+oEcnt);
  rwse_deg<<<GN, 256, 0, stream>>>(ws+oA, ws+oDeg);
  rwse_csr<<<GN, 256, 0, stream>>>(ws+oA, ws+oDeg, wsi+oMidx, ws+oMw, wsi+oMcnt);
  p0_init<<<32768, 256, 0, stream>>>(ws+oP0);
  float* P[2] = { ws+oP0, ws+oP1 };
  for (int s = 0; s < WALKN; s++)
    rwse_step<<<GN*4, 256, 0, stream>>>(P[s&1], P[1-(s&1)], wsi+oMidx, ws+oMw, wsi+oMcnt, ws+oPe, s);

  // ---- input proj ----
  concat_kernel<<<(NN*50+255)/256, 256, 0, stream>>>(x, ws+oPe, ws+oXin);
  gemm_fused<50,false,false,false,false,false><<<512, 256, 0, stream>>>(
      ws+oXin, nullptr, in_W, in_b, nullptr, nullptr, nullptr, nullptr, nullptr, nullptr,
      ws+oH, 128, 1);

  wp_all<<<3, 256, 0, stream>>>(ep_W, ep_b, ge_W, ge_b, ws+oWp, ws+oBp);

  // ---- layers ----
  for (int i = 0; i < 3; i++){
    gine_aggr<<<NN/2, 256, 0, stream>>>(ws+oH, eattr, ei, wsi+oEcsr, wsi+oEcnt,
                                        ws+oWp + (size_t)i*1408, ws+oBp + (size_t)i*128, ws+oAg);
    // t1 = relu((h+aggr)@g1+b1)
    gemm_fused<128,true,false,true,false,false><<<512, 256, 0, stream>>>(
        ws+oH, ws+oAg, g1_W + (size_t)i*16384, g1_b + (size_t)i*128,
        nullptr, nullptr, nullptr, nullptr, nullptr, nullptr, ws+oT1, 128, 1);
    // h1 = BN1(t1@g2+b2 + h)
    gemm_fused<128,false,true,false,true,false><<<512, 256, 0, stream>>>(
        ws+oT1, nullptr, g2_W + (size_t)i*16384, g2_b + (size_t)i*128,
        ws+oH, nullptr, bn1g+(size_t)i*128, bn1b+(size_t)i*128, bn1m+(size_t)i*128, bn1v+(size_t)i*128,
        ws+oH1, 128, 1);
    // qkv
    gemm_fused<128,false,false,false,false,false><<<1536, 256, 0, stream>>>(
        ws+oH, nullptr, qkv_W + (size_t)i*49152, qkv_b + (size_t)i*384,
        nullptr, nullptr, nullptr, nullptr, nullptr, nullptr, ws+oQKV, 384, 3);
    attn_kernel<<<GN*4, 256, 0, stream>>>(ws+oQKV, ws+oOB);
    // out = BN2(o@oW+ob + h) + h1
    gemm_fused<128,false,true,false,true,true><<<512, 256, 0, stream>>>(
        ws+oOB, nullptr, o_W + (size_t)i*16384, o_b + (size_t)i*128,
        ws+oH, ws+oH1, bn2g+(size_t)i*128, bn2b+(size_t)i*128, bn2m+(size_t)i*128, bn2v+(size_t)i*128,
        ws+oOut, 128, 1);
    // t2 = relu(out@m1+b)
    gemm_fused<128,true,false,false,false,false><<<1024, 256, 0, stream>>>(
        ws+oOut, nullptr, m1_W + (size_t)i*32768, m1_b + (size_t)i*256,
        nullptr, nullptr, nullptr, nullptr, nullptr, nullptr, ws+oT2, 256, 2);
    // h = BN3(t2@m2+b + out)
    gemm_fused<256,false,true,false,true,false><<<512, 256, 0, stream>>>(
        ws+oT2, nullptr, m2_W + (size_t)i*32768, m2_b + (size_t)i*128,
        ws+oOut, nullptr, bn3g+(size_t)i*128, bn3b+(size_t)i*128, bn3m+(size_t)i*128, bn3v+(size_t)i*128,
        ws+oH, 128, 1);
  }

  head_kernel<<<GN, 256, 0, stream>>>(ws+oH, h1_W, h1_b, h2_W, h2_b, out);
}

// Round 2
// 2102.144 us; speedup vs baseline: 1.7131x; 1.7131x over previous
//
#include <hip/hip_runtime.h>

#define GN   128      // graphs
#define GP   256      // nodes per graph
#define NN   32768    // total nodes
#define NEDGE 262144  // total edges
#define WALKN 20

// ============================================================
// RWSE: build A (dense counts) + edge dst-CSR
// ============================================================
__global__ __launch_bounds__(256) void build_edges(const int* __restrict__ ei, float* __restrict__ A,
                                                   int* __restrict__ Ecsr, int* __restrict__ Ecnt){
  int e = blockIdx.x*256 + threadIdx.x;
  int s = ei[e], d = ei[NEDGE + e];
  int g = s >> 8;
  atomicAdd(&A[((size_t)g<<16) + ((size_t)(s&255)<<8) + (size_t)(d&255)], 1.0f);
  int pos = atomicAdd(&Ecnt[d], 1);
  if (pos < 64) Ecsr[((size_t)d<<6) + pos] = e;
}

// add self loops + out-degree (row sums, clipped >=1)
__global__ __launch_bounds__(256) void rwse_deg(float* __restrict__ A, float* __restrict__ deg){
  int g = blockIdx.x, r = threadIdx.x;
  float* row = A + ((size_t)g<<16) + ((size_t)r<<8);
  row[r] += 1.0f;
  float s = 0.f;
  for (int c = 0; c < 256; c += 4){
    float4 v = *(const float4*)&row[c];
    s += v.x + v.y + v.z + v.w;
  }
  deg[(g<<8)+r] = fmaxf(s, 1.0f);
}

// Compacted, 4-padded CSR over rows of M (M[c][r] = A[r][c]/deg[r]).
// entries[g][k] = (idx_as_float, w) pairs; row_ptr[g][c]..row_ptr[g][c+1].
// All row segments are multiples of 4 entries (zero-padded) and 4-aligned,
// so the consumer can unroll by 4 with float4 loads.
__global__ __launch_bounds__(256) void rwse_csr2(const float* __restrict__ A, const float* __restrict__ deg,
                                                 int* __restrict__ row_ptr, float2* __restrict__ entries){
  int g = blockIdx.x, c = threadIdx.x;
  __shared__ float degs[256];
  __shared__ int cnts[256];
  __shared__ int offs[257];
  degs[c] = deg[(g<<8)+c];
  __syncthreads();
  const float* Ag = A + ((size_t)g<<16);
  int nnz = 0;
  for (int r = 0; r < 256; r++)
    if (Ag[((size_t)r<<8)+c] > 0.f) nnz++;
  cnts[c] = (nnz + 3) & ~3;
  __syncthreads();
  if (c == 0){
    int acc = 0;
    for (int i = 0; i < 256; i++){ offs[i] = acc; acc += cnts[i]; }
    offs[256] = acc;
  }
  __syncthreads();
  int off = offs[c];
  int cntp = cnts[c];
  float2* eb = entries + ((size_t)g<<12);
  int k = 0;
  for (int r = 0; r < 256; r++){
    float a = Ag[((size_t)r<<8)+c];
    if (a > 0.f){
      float2 e; e.x = __int_as_float(r); e.y = a / degs[r];
      eb[off + k] = e; k++;
    }
  }
  for (; k < cntp; k++){ float2 e; e.x = __int_as_float(0); e.y = 0.f; eb[off+k] = e; }
  row_ptr[g*257 + c] = off;
  if (c == 0) row_ptr[g*257 + 256] = offs[256];
}

// All 20 walk steps fused; P column-slice LDS-resident (columns evolve
// independently: p_{k+1} = M p_k per column). Single 64KB buffer via
// register staging -> 2 blocks/CU, 16 waves/CU.
__global__ __launch_bounds__(512, 4) void rwse_fused(const int* __restrict__ row_ptr,
                                                     const float2* __restrict__ entries,
                                                     float* __restrict__ pe){
  __shared__ float P[256][64];     // 64 KB
  int g  = blockIdx.x >> 2;
  int cb = (blockIdx.x & 3) << 6;
  int tid = threadIdx.x;
  int wave = tid >> 6, ln = tid & 63;
  int base = wave * 32;            // this wave's 32 output rows
  // init P = I slice
  #pragma unroll
  for (int i = 0; i < 32; i++)
    P[base + i][ln] = ((base + i) == cb + ln) ? 1.f : 0.f;
  // row_ptr[base..base+32] cached in lanes 0..32
  int rv = row_ptr[g*257 + base + (ln <= 32 ? ln : 32)];
  const float4* eb4 = (const float4*)(entries + ((size_t)g<<12));
  __syncthreads();
  for (int s = 0; s < WALKN; s++){
    float acc[32];
    #pragma unroll
    for (int i = 0; i < 32; i++){
      int beg = __shfl(rv, i);
      int end = __shfl(rv, i + 1);
      float a = 0.f;
      for (int j4 = beg >> 1; j4 < (end >> 1); j4 += 2){
        float4 e0 = eb4[j4];
        float4 e1 = eb4[j4 + 1];
        a += e0.y * P[__float_as_int(e0.x)][ln];
        a += e0.w * P[__float_as_int(e0.z)][ln];
        a += e1.y * P[__float_as_int(e1.x)][ln];
        a += e1.w * P[__float_as_int(e1.z)][ln];
      }
      acc[i] = a;
    }
    __syncthreads();                 // everyone done reading P
    #pragma unroll
    for (int i = 0; i < 32; i++){
      int c = base + i;
      P[c][ln] = acc[i];
      if (cb + ln == c) pe[(size_t)((g<<8)+c)*WALKN + s] = acc[i];
    }
    __syncthreads();                 // writes visible before next step
  }
}

// ============================================================
// concat [x | pe] -> xin [N,50]
// ============================================================
__global__ __launch_bounds__(256) void concat_kernel(const float* __restrict__ x, const float* __restrict__ pe,
                                                     float* __restrict__ xin){
  int idx = blockIdx.x*256 + threadIdx.x;
  if (idx >= NN*50) return;
  int row = idx / 50, c = idx % 50;
  xin[idx] = (c < 30) ? x[(size_t)row*30 + c] : pe[(size_t)row*20 + (c-30)];
}

// ============================================================
// Generic fused GEMM: Y = [BN]( [relu]( (X1[+X2]) @ W + b ) [+R] ) [+R2]
//   64-row x 128-col tile, k-tile 64, fp32
// ============================================================
template<int CIN, bool RELU, bool BN, bool HAS_X2, bool HAS_R, bool HAS_R2>
__global__ __launch_bounds__(256, 2) void gemm_fused(
    const float* __restrict__ X1, const float* __restrict__ X2,
    const float* __restrict__ W, const float* __restrict__ bias,
    const float* __restrict__ Rp, const float* __restrict__ R2p,
    const float* __restrict__ bng, const float* __restrict__ bnb,
    const float* __restrict__ bnm, const float* __restrict__ bnv,
    float* __restrict__ Y, int ldY, int colTiles)
{
  __shared__ __align__(16) float Wt[64][128];    // 32KB
  __shared__ __align__(16) float XtT[64][68];    // 17.4KB, transposed, padded
  int bt = blockIdx.x;
  int row0 = (bt / colTiles) * 64;
  int c0   = (bt % colTiles) * 128;
  int tid = threadIdx.x;
  int cq = tid & 15, rg = tid >> 4;
  int c8 = cq * 8;
  float acc[4][8];
  #pragma unroll
  for (int j = 0; j < 4; j++)
    #pragma unroll
    for (int cc = 0; cc < 8; cc++) acc[j][cc] = 0.f;

  for (int k0 = 0; k0 < CIN; k0 += 64){
    #pragma unroll 8
    for (int t = 0; t < 32; t++){        // Wt: 8192 elems
      int idx = tid + t*256;
      int kk = idx >> 7, cc = idx & 127;
      float v = 0.f;
      if (k0 + kk < CIN) v = W[(size_t)(k0+kk)*ldY + c0 + cc];
      Wt[kk][cc] = v;
    }
    #pragma unroll 8
    for (int t = 0; t < 16; t++){        // XtT: 4096 elems (stored transposed)
      int idx = tid + t*256;
      int rr = idx >> 6, kk = idx & 63;
      float v = 0.f;
      if (k0 + kk < CIN){
        size_t off = (size_t)(row0+rr)*CIN + k0 + kk;
        v = X1[off];
        if (HAS_X2) v += X2[off];
      }
      XtT[kk][rr] = v;
    }
    __syncthreads();
    #pragma unroll 8
    for (int k = 0; k < 64; k++){
      float4 xv = *(const float4*)&XtT[k][rg*4];
      float4 w0 = *(const float4*)&Wt[k][c8];
      float4 w1 = *(const float4*)&Wt[k][c8+4];
      acc[0][0] += xv.x*w0.x; acc[0][1] += xv.x*w0.y; acc[0][2] += xv.x*w0.z; acc[0][3] += xv.x*w0.w;
      acc[0][4] += xv.x*w1.x; acc[0][5] += xv.x*w1.y; acc[0][6] += xv.x*w1.z; acc[0][7] += xv.x*w1.w;
      acc[1][0] += xv.y*w0.x; acc[1][1] += xv.y*w0.y; acc[1][2] += xv.y*w0.z; acc[1][3] += xv.y*w0.w;
      acc[1][4] += xv.y*w1.x; acc[1][5] += xv.y*w1.y; acc[1][6] += xv.y*w1.z; acc[1][7] += xv.y*w1.w;
      acc[2][0] += xv.z*w0.x; acc[2][1] += xv.z*w0.y; acc[2][2] += xv.z*w0.z; acc[2][3] += xv.z*w0.w;
      acc[2][4] += xv.z*w1.x; acc[2][5] += xv.z*w1.y; acc[2][6] += xv.z*w1.z; acc[2][7] += xv.z*w1.w;
      acc[3][0] += xv.w*w0.x; acc[3][1] += xv.w*w0.y; acc[3][2] += xv.w*w0.z; acc[3][3] += xv.w*w0.w;
      acc[3][4] += xv.w*w1.x; acc[3][5] += xv.w*w1.y; acc[3][6] += xv.w*w1.z; acc[3][7] += xv.w*w1.w;
    }
    __syncthreads();
  }
  #pragma unroll
  for (int j = 0; j < 4; j++){
    int r = row0 + rg*4 + j;
    #pragma unroll
    for (int cc = 0; cc < 8; cc++){
      int col = c0 + c8 + cc;
      float v = acc[j][cc] + bias[col];
      if (RELU) v = fmaxf(v, 0.f);
      if (HAS_R) v += Rp[(size_t)r*ldY + col];
      if (BN)   v = (v - bnm[col]) * rsqrtf(bnv[col] + 1e-5f) * bng[col] + bnb[col];
      if (HAS_R2) v += R2p[(size_t)r*ldY + col];
      Y[(size_t)r*ldY + col] = v;
    }
  }
}

// ============================================================
// per-layer collapsed edge weights: Wp = ep_W @ ge_W[i], bp = ep_b @ ge_W[i] + ge_b[i]
// ============================================================
__global__ __launch_bounds__(256) void wp_all(const float* __restrict__ epW, const float* __restrict__ epb,
                                              const float* __restrict__ geW, const float* __restrict__ geb,
                                              float* __restrict__ Wp, float* __restrict__ bp){
  int i = blockIdx.x;
  const float* gw = geW + (size_t)i*16384;
  float* wp = Wp + (size_t)i*1408;
  int tid = threadIdx.x;
  for (int idx = tid; idx < 1408; idx += 256){
    int t = idx >> 7, c = idx & 127;
    float s = 0.f;
    for (int k = 0; k < 128; k++) s += epW[t*128+k] * gw[(size_t)k*128 + c];
    wp[idx] = s;
  }
  if (tid < 128){
    float s = geb[(size_t)i*128 + tid];
    for (int k = 0; k < 128; k++) s += epb[k] * gw[(size_t)k*128 + tid];
    bp[(size_t)i*128 + tid] = s;
  }
}

// ============================================================
// GINE aggregation (no atomics, dst-CSR): aggr[n] = sum_e relu(h[src]+edge_attr[e]@Wp+bp)
// ============================================================
__global__ __launch_bounds__(256) void gine_aggr(const float* __restrict__ h, const float* __restrict__ ea,
                                                 const int* __restrict__ ei, const int* __restrict__ Ecsr,
                                                 const int* __restrict__ Ecnt,
                                                 const float* __restrict__ Wp, const float* __restrict__ bp,
                                                 float* __restrict__ aggr){
  int n = blockIdx.x*2 + (threadIdx.x >> 7);
  int ch = threadIdx.x & 127;
  int cnt = Ecnt[n]; if (cnt > 64) cnt = 64;
  float wreg[11];
  #pragma unroll
  for (int t = 0; t < 11; t++) wreg[t] = Wp[t*128 + ch];
  float bpc = bp[ch];
  float acc = 0.f;
  for (int j = 0; j < cnt; j++){
    int e = Ecsr[((size_t)n<<6) + j];
    int s = ei[e];
    const float* eap = ea + (size_t)e*11;
    float v = bpc;
    #pragma unroll
    for (int t = 0; t < 11; t++) v += eap[t] * wreg[t];
    v += h[(size_t)s*128 + ch];
    acc += fmaxf(v, 0.f);
  }
  aggr[(size_t)n*128 + ch] = acc;
}

// ============================================================
// attention: one block per (graph, head), flash-style, 1 query row / thread
// ============================================================
__global__ __launch_bounds__(256) void attn_kernel(const float* __restrict__ qkv, float* __restrict__ o){
  __shared__ __align__(16) float Ks[256*32];   // 32KB
  __shared__ __align__(16) float Vs[256*32];   // 32KB
  int g = blockIdx.x >> 2, hh = blockIdx.x & 3;
  int tid = threadIdx.x;
  #pragma unroll
  for (int t = 0; t < 8; t++){
    int idx = tid + t*256;               // float4 index over 2048
    int row = idx >> 3, d4 = idx & 7;
    size_t rb = (size_t)((g<<8)+row)*384;
    ((float4*)Ks)[idx] = *(const float4*)(qkv + rb + 128 + hh*32 + d4*4);
    ((float4*)Vs)[idx] = *(const float4*)(qkv + rb + 256 + hh*32 + d4*4);
  }
  float q[32];
  {
    const float4* qr = (const float4*)(qkv + (size_t)((g<<8)+tid)*384 + hh*32);
    #pragma unroll
    for (int d4 = 0; d4 < 8; d4++){
      float4 t = qr[d4];
      q[d4*4]=t.x; q[d4*4+1]=t.y; q[d4*4+2]=t.z; q[d4*4+3]=t.w;
    }
  }
  __syncthreads();
  float m = -1e30f, l = 0.f;
  float accv[32];
  #pragma unroll
  for (int d = 0; d < 32; d++) accv[d] = 0.f;
  for (int j = 0; j < 256; j++){
    float s = 0.f;
    #pragma unroll
    for (int d4 = 0; d4 < 8; d4++){
      float4 kv = ((const float4*)Ks)[j*8 + d4];
      s += q[d4*4]*kv.x + q[d4*4+1]*kv.y + q[d4*4+2]*kv.z + q[d4*4+3]*kv.w;
    }
    s *= 0.17677669529663687f;           // 32^-0.5
    float nm = fmaxf(m, s);
    float alpha = __expf(m - nm);
    float p = __expf(s - nm);
    l = l*alpha + p;
    #pragma unroll
    for (int d4 = 0; d4 < 8; d4++){
      float4 vv = ((const float4*)Vs)[j*8 + d4];
      accv[d4*4]   = accv[d4*4]  *alpha + p*vv.x;
      accv[d4*4+1] = accv[d4*4+1]*alpha + p*vv.y;
      accv[d4*4+2] = accv[d4*4+2]*alpha + p*vv.z;
      accv[d4*4+3] = accv[d4*4+3]*alpha + p*vv.w;
    }
    m = nm;
  }
  float inv = 1.f / l;
  float* orow = o + (size_t)((g<<8)+tid)*128 + hh*32;
  #pragma unroll
  for (int d4 = 0; d4 < 8; d4++){
    float4 t;
    t.x = accv[d4*4]*inv; t.y = accv[d4*4+1]*inv; t.z = accv[d4*4+2]*inv; t.w = accv[d4*4+3]*inv;
    *(float4*)(orow + d4*4) = t;
  }
}

// ============================================================
// mean-pool + 2-layer head
// ============================================================
__global__ __launch_bounds__(256) void head_kernel(const float* __restrict__ h,
                                                   const float* __restrict__ W1, const float* __restrict__ b1,
                                                   const float* __restrict__ W2, const float* __restrict__ b2,
                                                   float* __restrict__ out){
  int g = blockIdx.x, tid = threadIdx.x;
  int c = tid & 127, half = tid >> 7;
  __shared__ float part[2][128];
  __shared__ float pool[128];
  __shared__ float hid[64];
  float s = 0.f;
  for (int n = half*128; n < half*128 + 128; n++)
    s += h[(size_t)((g<<8)+n)*128 + c];
  part[half][c] = s;
  __syncthreads();
  if (tid < 128) pool[tid] = (part[0][tid] + part[1][tid]) * (1.f/256.f);
  __syncthreads();
  if (tid < 64){
    float v = b1[tid];
    for (int k = 0; k < 128; k++) v += pool[k] * W1[k*64 + tid];
    hid[tid] = fmaxf(v, 0.f);
  }
  __syncthreads();
  if (tid == 0){
    float v = b2[0];
    for (int k = 0; k < 64; k++) v += hid[k] * W2[k];
    out[g] = v;
  }
}

// ============================================================
extern "C" void kernel_launch(void* const* d_in, const int* in_sizes, int n_in,
                              void* d_out, int out_size, void* d_ws, size_t ws_size,
                              hipStream_t stream){
  (void)in_sizes; (void)n_in; (void)out_size; (void)ws_size;
  const float* x      = (const float*)d_in[0];
  const float* eattr  = (const float*)d_in[1];
  const float* in_W   = (const float*)d_in[2];
  const float* in_b   = (const float*)d_in[3];
  const float* ep_W   = (const float*)d_in[4];
  const float* ep_b   = (const float*)d_in[5];
  const float* ge_W   = (const float*)d_in[6];
  const float* ge_b   = (const float*)d_in[7];
  const float* g1_W   = (const float*)d_in[8];
  const float* g1_b   = (const float*)d_in[9];
  const float* g2_W   = (const float*)d_in[10];
  const float* g2_b   = (const float*)d_in[11];
  const float* qkv_W  = (const float*)d_in[12];
  const float* qkv_b  = (const float*)d_in[13];
  const float* o_W    = (const float*)d_in[14];
  const float* o_b    = (const float*)d_in[15];
  const float* bn1g = (const float*)d_in[16]; const float* bn1b = (const float*)d_in[17];
  const float* bn1m = (const float*)d_in[18]; const float* bn1v = (const float*)d_in[19];
  const float* bn2g = (const float*)d_in[20]; const float* bn2b = (const float*)d_in[21];
  const float* bn2m = (const float*)d_in[22]; const float* bn2v = (const float*)d_in[23];
  const float* bn3g = (const float*)d_in[24]; const float* bn3b = (const float*)d_in[25];
  const float* bn3m = (const float*)d_in[26]; const float* bn3v = (const float*)d_in[27];
  const float* m1_W = (const float*)d_in[28]; const float* m1_b = (const float*)d_in[29];
  const float* m2_W = (const float*)d_in[30]; const float* m2_b = (const float*)d_in[31];
  const float* h1_W = (const float*)d_in[32]; const float* h1_b = (const float*)d_in[33];
  const float* h2_W = (const float*)d_in[34]; const float* h2_b = (const float*)d_in[35];
  const int*   ei   = (const int*)d_in[36];
  float* out = (float*)d_out;
  float* ws  = (float*)d_ws;
  int*   wsi = (int*)d_ws;

  // ---- workspace layout (element offsets) ----
  // RWSE region (reused after RWSE completes):
  const size_t oA    = 0;                        // 8,388,608 fp32 (dense A)
  const size_t oEnt  = 8388608;                  // 1,048,576 fp32 (128 x 4096 float2)
  const size_t oRp   = 9437184;                  // 32,896 int
  // overlays once RWSE is done:
  const size_t oQKV  = 0;                        // 12,582,912
  const size_t oT2   = 12582912;                 // 8,388,608
  const size_t oOB   = 20971520;                 // 4,194,304  -> ends 25,165,824
  // persistent region:
  const size_t oDeg  = 25165824;                 // 32,768
  const size_t oPe   = oDeg  + 32768;            // 655,360
  const size_t oXin  = oPe   + 655360;           // 1,638,400
  const size_t oH    = oXin  + 1638400;          // 4,194,304
  const size_t oAg   = oH    + 4194304;
  const size_t oT1   = oAg   + 4194304;
  const size_t oH1   = oT1   + 4194304;
  const size_t oOut  = oH1   + 4194304;
  const size_t oWp   = oOut  + 4194304;          // 4,224
  const size_t oBp   = oWp   + 4224;             // 384
  const size_t oEcsr = oBp   + 384;              // 2,097,152 int
  const size_t oEcnt = oEcsr + 2097152;          // 32,768 int

  // ---- RWSE ----
  hipMemsetAsync(ws + oA, 0, 8388608*sizeof(float), stream);
  hipMemsetAsync(wsi + oEcnt, 0, 32768*sizeof(int), stream);
  build_edges<<<NEDGE/256, 256, 0, stream>>>(ei, ws+oA, wsi+oEcsr, wsi+oEcnt);
  rwse_deg<<<GN, 256, 0, stream>>>(ws+oA, ws+oDeg);
  rwse_csr2<<<GN, 256, 0, stream>>>(ws+oA, ws+oDeg, wsi+oRp, (float2*)(ws+oEnt));
  rwse_fused<<<GN*4, 512, 0, stream>>>(wsi+oRp, (const float2*)(ws+oEnt), ws+oPe);

  // ---- input proj ----
  concat_kernel<<<(NN*50+255)/256, 256, 0, stream>>>(x, ws+oPe, ws+oXin);
  gemm_fused<50,false,false,false,false,false><<<512, 256, 0, stream>>>(
      ws+oXin, nullptr, in_W, in_b, nullptr, nullptr, nullptr, nullptr, nullptr, nullptr,
      ws+oH, 128, 1);

  wp_all<<<3, 256, 0, stream>>>(ep_W, ep_b, ge_W, ge_b, ws+oWp, ws+oBp);

  // ---- layers ----
  for (int i = 0; i < 3; i++){
    gine_aggr<<<NN/2, 256, 0, stream>>>(ws+oH, eattr, ei, wsi+oEcsr, wsi+oEcnt,
                                        ws+oWp + (size_t)i*1408, ws+oBp + (size_t)i*128, ws+oAg);
    // t1 = relu((h+aggr)@g1+b1)
    gemm_fused<128,true,false,true,false,false><<<512, 256, 0, stream>>>(
        ws+oH, ws+oAg, g1_W + (size_t)i*16384, g1_b + (size_t)i*128,
        nullptr, nullptr, nullptr, nullptr, nullptr, nullptr, ws+oT1, 128, 1);
    // h1 = BN1(t1@g2+b2 + h)
    gemm_fused<128,false,true,false,true,false><<<512, 256, 0, stream>>>(
        ws+oT1, nullptr, g2_W + (size_t)i*16384, g2_b + (size_t)i*128,
        ws+oH, nullptr, bn1g+(size_t)i*128, bn1b+(size_t)i*128, bn1m+(size_t)i*128, bn1v+(size_t)i*128,
        ws+oH1, 128, 1);
    // qkv
    gemm_fused<128,false,false,false,false,false><<<1536, 256, 0, stream>>>(
        ws+oH, nullptr, qkv_W + (size_t)i*49152, qkv_b + (size_t)i*384,
        nullptr, nullptr, nullptr, nullptr, nullptr, nullptr, ws+oQKV, 384, 3);
    attn_kernel<<<GN*4, 256, 0, stream>>>(ws+oQKV, ws+oOB);
    // out = BN2(o@oW+ob + h) + h1
    gemm_fused<128,false,true,false,true,true><<<512, 256, 0, stream>>>(
        ws+oOB, nullptr, o_W + (size_t)i*16384, o_b + (size_t)i*128,
        ws+oH, ws+oH1, bn2g+(size_t)i*128, bn2b+(size_t)i*128, bn2m+(size_t)i*128, bn2v+(size_t)i*128,
        ws+oOut, 128, 1);
    // t2 = relu(out@m1+b)
    gemm_fused<128,true,false,false,false,false><<<1024, 256, 0, stream>>>(
        ws+oOut, nullptr, m1_W + (size_t)i*32768, m1_b + (size_t)i*256,
        nullptr, nullptr, nullptr, nullptr, nullptr, nullptr, ws+oT2, 256, 2);
    // h = BN3(t2@m2+b + out)
    gemm_fused<256,false,true,false,true,false><<<512, 256, 0, stream>>>(
        ws+oT2, nullptr, m2_W + (size_t)i*32768, m2_b + (size_t)i*128,
        ws+oOut, nullptr, bn3g+(size_t)i*128, bn3b+(size_t)i*128, bn3m+(size_t)i*128, bn3v+(size_t)i*128,
        ws+oH, 128, 1);
  }

  head_kernel<<<GN, 256, 0, stream>>>(ws+oH, h1_W, h1_b, h2_W, h2_b, out);
}

// Round 3
// 1310.973 us; speedup vs baseline: 2.7470x; 1.6035x over previous
//
#include <hip/hip_runtime.h>

#define GN   128      // graphs
#define GP   256      // nodes per graph
#define NN   32768    // total nodes
#define NEDGE 262144  // total edges
#define WALKN 20

typedef __attribute__((ext_vector_type(8))) short bfrag;   // 8 bf16 (4 VGPRs)
typedef __attribute__((ext_vector_type(4))) float ffrag;   // 4 fp32 acc

__device__ __forceinline__ ushort f2b(float f){
  unsigned u = __float_as_uint(f);
  u += 0x7fffu + ((u >> 16) & 1u);      // RNE
  return (ushort)(u >> 16);
}

// ============================================================
// RWSE: build A (dense counts) + edge dst-CSR
// ============================================================
__global__ __launch_bounds__(256) void build_edges(const int* __restrict__ ei, float* __restrict__ A,
                                                   int* __restrict__ Ecsr, int* __restrict__ Ecnt){
  int e = blockIdx.x*256 + threadIdx.x;
  int s = ei[e], d = ei[NEDGE + e];
  int g = s >> 8;
  atomicAdd(&A[((size_t)g<<16) + ((size_t)(s&255)<<8) + (size_t)(d&255)], 1.0f);
  int pos = atomicAdd(&Ecnt[d], 1);
  if (pos < 64) Ecsr[((size_t)d<<6) + pos] = e;
}

__global__ __launch_bounds__(256) void rwse_deg(float* __restrict__ A, float* __restrict__ deg){
  int g = blockIdx.x, r = threadIdx.x;
  float* row = A + ((size_t)g<<16) + ((size_t)r<<8);
  row[r] += 1.0f;
  float s = 0.f;
  for (int c = 0; c < 256; c += 4){
    float4 v = *(const float4*)&row[c];
    s += v.x + v.y + v.z + v.w;
  }
  deg[(g<<8)+r] = fmaxf(s, 1.0f);
}

// Compacted, 4-padded CSR over rows of M (M[c][r] = A[r][c]/deg[r]).
__global__ __launch_bounds__(256) void rwse_csr2(const float* __restrict__ A, const float* __restrict__ deg,
                                                 int* __restrict__ row_ptr, float2* __restrict__ entries){
  int g = blockIdx.x, c = threadIdx.x;
  __shared__ float degs[256];
  __shared__ int cnts[256];
  __shared__ int offs[257];
  degs[c] = deg[(g<<8)+c];
  __syncthreads();
  const float* Ag = A + ((size_t)g<<16);
  int nnz = 0;
  for (int r = 0; r < 256; r++)
    if (Ag[((size_t)r<<8)+c] > 0.f) nnz++;
  cnts[c] = (nnz + 3) & ~3;
  __syncthreads();
  if (c == 0){
    int acc = 0;
    for (int i = 0; i < 256; i++){ offs[i] = acc; acc += cnts[i]; }
    offs[256] = acc;
  }
  __syncthreads();
  int off = offs[c];
  int cntp = cnts[c];
  float2* eb = entries + ((size_t)g<<12);
  int k = 0;
  for (int r = 0; r < 256; r++){
    float a = Ag[((size_t)r<<8)+c];
    if (a > 0.f){
      float2 e; e.x = __int_as_float(r); e.y = a / degs[r];
      eb[off + k] = e; k++;
    }
  }
  for (; k < cntp; k++){ float2 e; e.x = __int_as_float(0); e.y = 0.f; eb[off+k] = e; }
  row_ptr[g*257 + c] = off;
  if (c == 0) row_ptr[g*257 + 256] = offs[256];
}

__global__ __launch_bounds__(512, 4) void rwse_fused(const int* __restrict__ row_ptr,
                                                     const float2* __restrict__ entries,
                                                     float* __restrict__ pe){
  __shared__ float P[256][64];     // 64 KB
  int g  = blockIdx.x >> 2;
  int cb = (blockIdx.x & 3) << 6;
  int tid = threadIdx.x;
  int wave = tid >> 6, ln = tid & 63;
  int base = wave * 32;
  #pragma unroll
  for (int i = 0; i < 32; i++)
    P[base + i][ln] = ((base + i) == cb + ln) ? 1.f : 0.f;
  int rv = row_ptr[g*257 + base + (ln <= 32 ? ln : 32)];
  const float4* eb4 = (const float4*)(entries + ((size_t)g<<12));
  __syncthreads();
  for (int s = 0; s < WALKN; s++){
    float acc[32];
    #pragma unroll
    for (int i = 0; i < 32; i++){
      int beg = __shfl(rv, i);
      int end = __shfl(rv, i + 1);
      float a = 0.f;
      for (int j4 = beg >> 1; j4 < (end >> 1); j4 += 2){
        float4 e0 = eb4[j4];
        float4 e1 = eb4[j4 + 1];
        a += e0.y * P[__float_as_int(e0.x)][ln];
        a += e0.w * P[__float_as_int(e0.z)][ln];
        a += e1.y * P[__float_as_int(e1.x)][ln];
        a += e1.w * P[__float_as_int(e1.z)][ln];
      }
      acc[i] = a;
    }
    __syncthreads();
    #pragma unroll
    for (int i = 0; i < 32; i++){
      int c = base + i;
      P[c][ln] = acc[i];
      if (cb + ln == c) pe[(size_t)((g<<8)+c)*WALKN + s] = acc[i];
    }
    __syncthreads();
  }
}

// ============================================================
// concat [x | pe | 0pad] -> xin [N,64]
// ============================================================
__global__ __launch_bounds__(256) void concat_kernel(const float* __restrict__ x, const float* __restrict__ pe,
                                                     float* __restrict__ xin){
  int idx = blockIdx.x*256 + threadIdx.x;    // NN*64
  int row = idx >> 6, c = idx & 63;
  float v = 0.f;
  if (c < 30) v = x[(size_t)row*30 + c];
  else if (c < 50) v = pe[(size_t)row*20 + (c-30)];
  xin[idx] = v;
}

// ============================================================
// prep: all weights -> bf16 transposed [N][Kp] (B-operand layout)
// ============================================================
__global__ __launch_bounds__(256) void prep_wt(const float* __restrict__ in_W, const float* __restrict__ g1_W,
                                               const float* __restrict__ g2_W, const float* __restrict__ qkv_W,
                                               const float* __restrict__ o_W, const float* __restrict__ m1_W,
                                               const float* __restrict__ m2_W, ushort* __restrict__ wt){
  int rgn = blockIdx.y;
  const float* src; int K, N, Kp; size_t dst;
  if (rgn == 0){ src = in_W; K=50; N=128; Kp=64; dst = 0; }
  else if (rgn <= 3){ int i=rgn-1;  src = g1_W + (size_t)i*16384; K=128; N=128; Kp=128; dst = 8192   + (size_t)i*16384; }
  else if (rgn <= 6){ int i=rgn-4;  src = g2_W + (size_t)i*16384; K=128; N=128; Kp=128; dst = 57344  + (size_t)i*16384; }
  else if (rgn <= 9){ int i=rgn-7;  src = qkv_W+ (size_t)i*49152; K=128; N=384; Kp=128; dst = 106496 + (size_t)i*49152; }
  else if (rgn <= 12){ int i=rgn-10; src = o_W  + (size_t)i*16384; K=128; N=128; Kp=128; dst = 253952 + (size_t)i*16384; }
  else if (rgn <= 15){ int i=rgn-13; src = m1_W + (size_t)i*32768; K=128; N=256; Kp=128; dst = 303104 + (size_t)i*32768; }
  else               { int i=rgn-16; src = m2_W + (size_t)i*32768; K=256; N=128; Kp=256; dst = 401408 + (size_t)i*32768; }
  int sz = N * Kp;
  int idx = blockIdx.x*256 + threadIdx.x;
  if (idx >= sz) return;
  int n = idx / Kp, kp = idx - n*Kp;
  float v = (kp < K) ? src[(size_t)kp*N + n] : 0.f;
  wt[dst + idx] = f2b(v);
}

// ============================================================
// bf16 MFMA GEMM: Y = [BN]( [relu]( (X1[+X2]) @ W + b ) [+R] ) [+R2]
//   64-row x 128-col tile, 4 waves (2x2), wave tile 32x64, 16x16x32 bf16
// ============================================================
template<int CINP, bool RELU, bool BN, bool HAS_X2, bool HAS_R, bool HAS_R2>
__global__ __launch_bounds__(256, 2) void gemm_mf(
    const float* __restrict__ X1, const float* __restrict__ X2,
    const ushort* __restrict__ WT, const float* __restrict__ bias,
    const float* __restrict__ Rp, const float* __restrict__ R2p,
    const float* __restrict__ bng, const float* __restrict__ bnb,
    const float* __restrict__ bnm, const float* __restrict__ bnv,
    float* __restrict__ Y, int ldY, int colTiles)
{
  constexpr int KT = (CINP > 128) ? 128 : CINP;
  constexpr int XS = KT + 8;                 // LDS row stride (bf16 elems)
  __shared__ ushort XA[64 * XS];
  __shared__ ushort WS[128 * XS];
  int bt = blockIdx.x;
  int row0 = (bt / colTiles) * 64;
  int c0   = (bt % colTiles) * 128;
  int tid = threadIdx.x;
  int lane = tid & 63, wave = tid >> 6;
  int l15 = lane & 15, quad = lane >> 4;
  int wr = wave >> 1, wc = wave & 1;

  ffrag acc[2][4];
  #pragma unroll
  for (int m = 0; m < 2; m++)
    #pragma unroll
    for (int n = 0; n < 4; n++)
      acc[m][n] = (ffrag){0.f,0.f,0.f,0.f};

  #pragma unroll
  for (int s = 0; s < CINP/KT; s++){
    // stage X tile -> bf16 LDS
    constexpr int F4PR = KT/4;
    #pragma unroll
    for (int it = 0; it < (64*F4PR)/256; it++){
      int idx = tid + it*256;
      int r = idx / F4PR, c4 = idx % F4PR;
      float4 v = *(const float4*)&X1[(size_t)(row0+r)*CINP + s*KT + c4*4];
      if (HAS_X2){
        float4 w = *(const float4*)&X2[(size_t)(row0+r)*CINP + s*KT + c4*4];
        v.x += w.x; v.y += w.y; v.z += w.z; v.w += w.w;
      }
      ushort4 b; b.x = f2b(v.x); b.y = f2b(v.y); b.z = f2b(v.z); b.w = f2b(v.w);
      *reinterpret_cast<ushort4*>(&XA[r*XS + c4*4]) = b;
    }
    // stage W tile (already bf16 [N][Kp]) -> LDS
    constexpr int U4PR = KT/8;
    #pragma unroll
    for (int it = 0; it < (128*U4PR)/256; it++){
      int idx = tid + it*256;
      int n = idx / U4PR, c8 = idx % U4PR;
      uint4 v = *(const uint4*)&WT[(size_t)(c0+n)*CINP + s*KT + c8*8];
      *reinterpret_cast<uint4*>(&WS[n*XS + c8*8]) = v;
    }
    __syncthreads();
    #pragma unroll
    for (int ks = 0; ks < KT/32; ks++){
      bfrag a[2], b[4];
      #pragma unroll
      for (int m = 0; m < 2; m++)
        a[m] = *reinterpret_cast<const bfrag*>(&XA[(32*wr + 16*m + l15)*XS + ks*32 + quad*8]);
      #pragma unroll
      for (int n = 0; n < 4; n++)
        b[n] = *reinterpret_cast<const bfrag*>(&WS[(64*wc + 16*n + l15)*XS + ks*32 + quad*8]);
      #pragma unroll
      for (int m = 0; m < 2; m++)
        #pragma unroll
        for (int n = 0; n < 4; n++)
          acc[m][n] = __builtin_amdgcn_mfma_f32_16x16x32_bf16(a[m], b[n], acc[m][n], 0, 0, 0);
    }
    __syncthreads();
  }
  // epilogue (fp32)
  #pragma unroll
  for (int m = 0; m < 2; m++)
    #pragma unroll
    for (int n = 0; n < 4; n++){
      int col = c0 + 64*wc + 16*n + l15;
      float bs = bias[col];
      float bnscale = 0.f, bnsh = 0.f;
      if (BN){ bnscale = rsqrtf(bnv[col] + 1e-5f) * bng[col]; bnsh = bnb[col] - bnm[col]*bnscale; }
      #pragma unroll
      for (int rg = 0; rg < 4; rg++){
        int r = row0 + 32*wr + 16*m + quad*4 + rg;
        float v = acc[m][n][rg] + bs;
        if (RELU) v = fmaxf(v, 0.f);
        if (HAS_R) v += Rp[(size_t)r*ldY + col];
        if (BN)   v = v*bnscale + bnsh;
        if (HAS_R2) v += R2p[(size_t)r*ldY + col];
        Y[(size_t)r*ldY + col] = v;
      }
    }
}

// ============================================================
// per-layer collapsed edge weights: Wp = ep_W @ ge_W[i], bp = ep_b @ ge_W[i] + ge_b[i]
// ============================================================
__global__ __launch_bounds__(256) void wp_all(const float* __restrict__ epW, const float* __restrict__ epb,
                                              const float* __restrict__ geW, const float* __restrict__ geb,
                                              float* __restrict__ Wp, float* __restrict__ bp){
  int i = blockIdx.x;
  const float* gw = geW + (size_t)i*16384;
  float* wp = Wp + (size_t)i*1408;
  int tid = threadIdx.x;
  for (int idx = tid; idx < 1408; idx += 256){
    int t = idx >> 7, c = idx & 127;
    float s = 0.f;
    for (int k = 0; k < 128; k++) s += epW[t*128+k] * gw[(size_t)k*128 + c];
    wp[idx] = s;
  }
  if (tid < 128){
    float s = geb[(size_t)i*128 + tid];
    for (int k = 0; k < 128; k++) s += epb[k] * gw[(size_t)k*128 + tid];
    bp[(size_t)i*128 + tid] = s;
  }
}

// ============================================================
// GINE aggregation (dst-CSR): aggr[n] = sum_e relu(h[src]+edge_attr[e]@Wp+bp)
// ============================================================
__global__ __launch_bounds__(256) void gine_aggr(const float* __restrict__ h, const float* __restrict__ ea,
                                                 const int* __restrict__ ei, const int* __restrict__ Ecsr,
                                                 const int* __restrict__ Ecnt,
                                                 const float* __restrict__ Wp, const float* __restrict__ bp,
                                                 float* __restrict__ aggr){
  int n = blockIdx.x*2 + (threadIdx.x >> 7);
  int ch = threadIdx.x & 127;
  int cnt = Ecnt[n]; if (cnt > 64) cnt = 64;
  float wreg[11];
  #pragma unroll
  for (int t = 0; t < 11; t++) wreg[t] = Wp[t*128 + ch];
  float bpc = bp[ch];
  float acc = 0.f;
  for (int j = 0; j < cnt; j++){
    int e = Ecsr[((size_t)n<<6) + j];
    int s = ei[e];
    const float* eap = ea + (size_t)e*11;
    float v = bpc;
    #pragma unroll
    for (int t = 0; t < 11; t++) v += eap[t] * wreg[t];
    v += h[(size_t)s*128 + ch];
    acc += fmaxf(v, 0.f);
  }
  aggr[(size_t)n*128 + ch] = acc;
}

// ============================================================
// MFMA attention: block per (graph, head); 4 waves, wave = 64 q rows
// ============================================================
__global__ __launch_bounds__(256, 2) void attn_mf(const float* __restrict__ qkv, float* __restrict__ o){
  __shared__ ushort Ks[256 * 40];        // K  [key][d]   20.5 KB
  __shared__ ushort Vt[32 * 264];        // V^T [d][key]  16.9 KB
  __shared__ ushort PA[4 * 16 * 264];    // P per wave [q][key] 33.8 KB
  int g = blockIdx.x >> 2, hh = blockIdx.x & 3;
  int tid = threadIdx.x, lane = tid & 63, w = tid >> 6;
  int l15 = lane & 15, quad = lane >> 4;
  const float* base = qkv + (size_t)(g<<8)*384;

  // stage K (bf16) and V^T (bf16)
  #pragma unroll
  for (int it = 0; it < 8; it++){
    int idx = tid + it*256;              // 2048 float4 over 256x32
    int key = idx >> 3, d4 = idx & 7;
    float4 kv = *(const float4*)&base[(size_t)key*384 + 128 + hh*32 + d4*4];
    ushort4 kb; kb.x=f2b(kv.x); kb.y=f2b(kv.y); kb.z=f2b(kv.z); kb.w=f2b(kv.w);
    *reinterpret_cast<ushort4*>(&Ks[key*40 + d4*4]) = kb;
    float4 vv = *(const float4*)&base[(size_t)key*384 + 256 + hh*32 + d4*4];
    Vt[(d4*4+0)*264 + key] = f2b(vv.x);
    Vt[(d4*4+1)*264 + key] = f2b(vv.y);
    Vt[(d4*4+2)*264 + key] = f2b(vv.z);
    Vt[(d4*4+3)*264 + key] = f2b(vv.w);
  }
  // Q fragments in registers (4 q-groups of 16 per wave)
  bfrag qf[4];
  #pragma unroll
  for (int qg = 0; qg < 4; qg++){
    int q = w*64 + qg*16 + l15;
    const float* qp = base + (size_t)q*384 + hh*32 + quad*8;
    float4 v0 = *(const float4*)qp;
    float4 v1 = *(const float4*)(qp + 4);
    bfrag t;
    t[0]=(short)f2b(v0.x); t[1]=(short)f2b(v0.y); t[2]=(short)f2b(v0.z); t[3]=(short)f2b(v0.w);
    t[4]=(short)f2b(v1.x); t[5]=(short)f2b(v1.y); t[6]=(short)f2b(v1.z); t[7]=(short)f2b(v1.w);
    qf[qg] = t;
  }
  __syncthreads();

  ushort* pw = &PA[w * 16 * 264];
  const float sc_ = 0.17677669529663687f;   // 32^-0.5
  for (int qg = 0; qg < 4; qg++){
    // S = Q K^T  (one K=32 MFMA per 16-key group)
    ffrag sc[16];
    #pragma unroll
    for (int kg = 0; kg < 16; kg++){
      bfrag bk = *reinterpret_cast<const bfrag*>(&Ks[(kg*16 + l15)*40 + quad*8]);
      ffrag z = (ffrag){0.f,0.f,0.f,0.f};
      sc[kg] = __builtin_amdgcn_mfma_f32_16x16x32_bf16(qf[qg], bk, z, 0, 0, 0);
    }
    // softmax over 256 keys per q-row (row = quad*4+rg, cols = kg*16+l15)
    float inv_l[4];
    #pragma unroll
    for (int rg = 0; rg < 4; rg++){
      float m = sc[0][rg];
      #pragma unroll
      for (int kg = 1; kg < 16; kg++) m = fmaxf(m, sc[kg][rg]);
      #pragma unroll
      for (int off = 1; off < 16; off <<= 1) m = fmaxf(m, __shfl_xor(m, off, 16));
      float ssum = 0.f;
      #pragma unroll
      for (int kg = 0; kg < 16; kg++){
        float p = __expf((sc[kg][rg] - m) * sc_);
        sc[kg][rg] = p; ssum += p;
      }
      #pragma unroll
      for (int off = 1; off < 16; off <<= 1) ssum += __shfl_xor(ssum, off, 16);
      inv_l[rg] = 1.f / ssum;
    }
    // P -> LDS (A-operand layout [q_local][key]); wave-private region
    #pragma unroll
    for (int kg = 0; kg < 16; kg++)
      #pragma unroll
      for (int rg = 0; rg < 4; rg++)
        pw[(quad*4 + rg)*264 + kg*16 + l15] = f2b(sc[kg][rg]);
    // O = P V
    ffrag oa[2];
    oa[0] = (ffrag){0.f,0.f,0.f,0.f};
    oa[1] = (ffrag){0.f,0.f,0.f,0.f};
    #pragma unroll
    for (int ks = 0; ks < 8; ks++){
      bfrag pa = *reinterpret_cast<const bfrag*>(&pw[l15*264 + ks*32 + quad*8]);
      #pragma unroll
      for (int n16 = 0; n16 < 2; n16++){
        bfrag bv = *reinterpret_cast<const bfrag*>(&Vt[(n16*16 + l15)*264 + ks*32 + quad*8]);
        oa[n16] = __builtin_amdgcn_mfma_f32_16x16x32_bf16(pa, bv, oa[n16], 0, 0, 0);
      }
    }
    #pragma unroll
    for (int n16 = 0; n16 < 2; n16++)
      #pragma unroll
      for (int rg = 0; rg < 4; rg++){
        int q = w*64 + qg*16 + quad*4 + rg;
        int col = hh*32 + n16*16 + l15;
        o[((size_t)(g<<8) + q)*128 + col] = oa[n16][rg] * inv_l[rg];
      }
  }
}

// ============================================================
// mean-pool + 2-layer head
// ============================================================
__global__ __launch_bounds__(256) void head_kernel(const float* __restrict__ h,
                                                   const float* __restrict__ W1, const float* __restrict__ b1,
                                                   const float* __restrict__ W2, const float* __restrict__ b2,
                                                   float* __restrict__ out){
  int g = blockIdx.x, tid = threadIdx.x;
  int c = tid & 127, half = tid >> 7;
  __shared__ float part[2][128];
  __shared__ float pool[128];
  __shared__ float hid[64];
  float s = 0.f;
  for (int n = half*128; n < half*128 + 128; n++)
    s += h[(size_t)((g<<8)+n)*128 + c];
  part[half][c] = s;
  __syncthreads();
  if (tid < 128) pool[tid] = (part[0][tid] + part[1][tid]) * (1.f/256.f);
  __syncthreads();
  if (tid < 64){
    float v = b1[tid];
    for (int k = 0; k < 128; k++) v += pool[k] * W1[k*64 + tid];
    hid[tid] = fmaxf(v, 0.f);
  }
  __syncthreads();
  if (tid == 0){
    float v = b2[0];
    for (int k = 0; k < 64; k++) v += hid[k] * W2[k];
    out[g] = v;
  }
}

// ============================================================
extern "C" void kernel_launch(void* const* d_in, const int* in_sizes, int n_in,
                              void* d_out, int out_size, void* d_ws, size_t ws_size,
                              hipStream_t stream){
  (void)in_sizes; (void)n_in; (void)out_size; (void)ws_size;
  const float* x      = (const float*)d_in[0];
  const float* eattr  = (const float*)d_in[1];
  const float* in_W   = (const float*)d_in[2];
  const float* in_b   = (const float*)d_in[3];
  const float* ep_W   = (const float*)d_in[4];
  const float* ep_b   = (const float*)d_in[5];
  const float* ge_W   = (const float*)d_in[6];
  const float* ge_b   = (const float*)d_in[7];
  const float* g1_W   = (const float*)d_in[8];
  const float* g1_b   = (const float*)d_in[9];
  const float* g2_W   = (const float*)d_in[10];
  const float* g2_b   = (const float*)d_in[11];
  const float* qkv_W  = (const float*)d_in[12];
  const float* qkv_b  = (const float*)d_in[13];
  const float* o_W    = (const float*)d_in[14];
  const float* o_b    = (const float*)d_in[15];
  const float* bn1g = (const float*)d_in[16]; const float* bn1b = (const float*)d_in[17];
  const float* bn1m = (const float*)d_in[18]; const float* bn1v = (const float*)d_in[19];
  const float* bn2g = (const float*)d_in[20]; const float* bn2b = (const float*)d_in[21];
  const float* bn2m = (const float*)d_in[22]; const float* bn2v = (const float*)d_in[23];
  const float* bn3g = (const float*)d_in[24]; const float* bn3b = (const float*)d_in[25];
  const float* bn3m = (const float*)d_in[26]; const float* bn3v = (const float*)d_in[27];
  const float* m1_W = (const float*)d_in[28]; const float* m1_b = (const float*)d_in[29];
  const float* m2_W = (const float*)d_in[30]; const float* m2_b = (const float*)d_in[31];
  const float* h1_W = (const float*)d_in[32]; const float* h1_b = (const float*)d_in[33];
  const float* h2_W = (const float*)d_in[34]; const float* h2_b = (const float*)d_in[35];
  const int*   ei   = (const int*)d_in[36];
  float* out = (float*)d_out;
  float* ws  = (float*)d_ws;
  int*   wsi = (int*)d_ws;

  // ---- workspace layout (fp32-element offsets) ----
  // RWSE-phase region (dead after rwse_fused):
  const size_t oA    = 0;            // 8,388,608
  const size_t oEnt  = 8388608;      // 1,048,576
  const size_t oRp   = 9437184;      // 32,896
  // overlays (post-RWSE): Xin [0..2.1M) -> later qkv [0..12.58M)
  const size_t oXin  = 0;            // NN*64 = 2,097,152
  const size_t oQKV  = 0;            // 12,582,912
  const size_t oT2   = 12582912;     // 8,388,608
  const size_t oOB   = 20971520;     // 4,194,304   (ends 25,165,824)
  // persistent:
  const size_t oDeg  = 25165824;     // 32,768
  const size_t oPe   = 25198592;     // 655,360
  const size_t oH    = 25853952;     // 4,194,304
  const size_t oAg   = 30048256;     // 4,194,304
  const size_t oT1   = 34242560;     // 4,194,304
  const size_t oH1   = 38436864;     // 4,194,304
  const size_t oOut  = 42631168;     // 4,194,304
  const size_t oWp   = 46825472;     // 4,224
  const size_t oBp   = 46829696;     // 384
  const size_t oEcsr = 46830080;     // 2,097,152 int
  const size_t oEcnt = 48927232;     // 32,768 int
  const size_t oWT   = 48960000;     // 499,712 ushort = 249,856 fp32 slots
  ushort* wt = (ushort*)(ws + oWT);

  // ---- RWSE (unchanged sparse path) ----
  hipMemsetAsync(ws + oA, 0, 8388608*sizeof(float), stream);
  hipMemsetAsync(wsi + oEcnt, 0, 32768*sizeof(int), stream);
  build_edges<<<NEDGE/256, 256, 0, stream>>>(ei, ws+oA, wsi+oEcsr, wsi+oEcnt);
  rwse_deg<<<GN, 256, 0, stream>>>(ws+oA, ws+oDeg);
  rwse_csr2<<<GN, 256, 0, stream>>>(ws+oA, ws+oDeg, wsi+oRp, (float2*)(ws+oEnt));
  rwse_fused<<<GN*4, 512, 0, stream>>>(wsi+oRp, (const float2*)(ws+oEnt), ws+oPe);

  // ---- weight prep (bf16 transposed) ----
  prep_wt<<<dim3(192, 19), 256, 0, stream>>>(in_W, g1_W, g2_W, qkv_W, o_W, m1_W, m2_W, wt);

  // ---- input proj ----
  concat_kernel<<<NN*64/256, 256, 0, stream>>>(x, ws+oPe, ws+oXin);
  gemm_mf<64,false,false,false,false,false><<<512, 256, 0, stream>>>(
      ws+oXin, nullptr, wt + 0, in_b, nullptr, nullptr, nullptr, nullptr, nullptr, nullptr,
      ws+oH, 128, 1);

  wp_all<<<3, 256, 0, stream>>>(ep_W, ep_b, ge_W, ge_b, ws+oWp, ws+oBp);

  // ---- layers ----
  for (int i = 0; i < 3; i++){
    gine_aggr<<<NN/2, 256, 0, stream>>>(ws+oH, eattr, ei, wsi+oEcsr, wsi+oEcnt,
                                        ws+oWp + (size_t)i*1408, ws+oBp + (size_t)i*128, ws+oAg);
    // t1 = relu((h+aggr)@g1+b1)
    gemm_mf<128,true,false,true,false,false><<<512, 256, 0, stream>>>(
        ws+oH, ws+oAg, wt + 8192 + (size_t)i*16384, g1_b + (size_t)i*128,
        nullptr, nullptr, nullptr, nullptr, nullptr, nullptr, ws+oT1, 128, 1);
    // h1 = BN1(t1@g2+b2 + h)
    gemm_mf<128,false,true,false,true,false><<<512, 256, 0, stream>>>(
        ws+oT1, nullptr, wt + 57344 + (size_t)i*16384, g2_b + (size_t)i*128,
        ws+oH, nullptr, bn1g+(size_t)i*128, bn1b+(size_t)i*128, bn1m+(size_t)i*128, bn1v+(size_t)i*128,
        ws+oH1, 128, 1);
    // qkv
    gemm_mf<128,false,false,false,false,false><<<1536, 256, 0, stream>>>(
        ws+oH, nullptr, wt + 106496 + (size_t)i*49152, qkv_b + (size_t)i*384,
        nullptr, nullptr, nullptr, nullptr, nullptr, nullptr, ws+oQKV, 384, 3);
    attn_mf<<<GN*4, 256, 0, stream>>>(ws+oQKV, ws+oOB);
    // out = BN2(o@oW+ob + h) + h1
    gemm_mf<128,false,true,false,true,true><<<512, 256, 0, stream>>>(
        ws+oOB, nullptr, wt + 253952 + (size_t)i*16384, o_b + (size_t)i*128,
        ws+oH, ws+oH1, bn2g+(size_t)i*128, bn2b+(size_t)i*128, bn2m+(size_t)i*128, bn2v+(size_t)i*128,
        ws+oOut, 128, 1);
    // t2 = relu(out@m1+b)
    gemm_mf<128,true,false,false,false,false><<<1024, 256, 0, stream>>>(
        ws+oOut, nullptr, wt + 303104 + (size_t)i*32768, m1_b + (size_t)i*256,
        nullptr, nullptr, nullptr, nullptr, nullptr, nullptr, ws+oT2, 256, 2);
    // h = BN3(t2@m2+b + out)
    gemm_mf<256,false,true,false,true,false><<<512, 256, 0, stream>>>(
        ws+oT2, nullptr, wt + 401408 + (size_t)i*32768, m2_b + (size_t)i*128,
        ws+oOut, nullptr, bn3g+(size_t)i*128, bn3b+(size_t)i*128, bn3m+(size_t)i*128, bn3v+(size_t)i*128,
        ws+oH, 128, 1);
  }

  head_kernel<<<GN, 256, 0, stream>>>(ws+oH, h1_W, h1_b, h2_W, h2_b, out);
}

// Round 4
// 1283.234 us; speedup vs baseline: 2.8063x; 1.0216x over previous
//
#include <hip/hip_runtime.h>

#define GN   128      // graphs
#define GP   256      // nodes per graph
#define NN   32768    // total nodes
#define NEDGE 262144  // total edges
#define WALKN 20

typedef __attribute__((ext_vector_type(8))) short bfrag;   // 8 bf16 (4 VGPRs)
typedef __attribute__((ext_vector_type(4))) float ffrag;   // 4 fp32 acc

__device__ __forceinline__ ushort f2b(float f){
  unsigned u = __float_as_uint(f);
  u += 0x7fffu + ((u >> 16) & 1u);      // RNE
  return (ushort)(u >> 16);
}

// ============================================================
// RWSE: build A (dense counts) + edge dst-CSR
// ============================================================
__global__ __launch_bounds__(256) void build_edges(const int* __restrict__ ei, float* __restrict__ A,
                                                   int* __restrict__ Ecsr, int* __restrict__ Ecnt){
  int e = blockIdx.x*256 + threadIdx.x;
  int s = ei[e], d = ei[NEDGE + e];
  int g = s >> 8;
  atomicAdd(&A[((size_t)g<<16) + ((size_t)(s&255)<<8) + (size_t)(d&255)], 1.0f);
  int pos = atomicAdd(&Ecnt[d], 1);
  if (pos < 64) Ecsr[((size_t)d<<6) + pos] = e;
}

// add self loops + out-degree (row sums, clipped >=1); also pe step0 = A[r][r]/deg
__global__ __launch_bounds__(256) void rwse_deg(float* __restrict__ A, float* __restrict__ deg,
                                                float* __restrict__ pe){
  int g = blockIdx.x, r = threadIdx.x;
  float* row = A + ((size_t)g<<16) + ((size_t)r<<8);
  row[r] += 1.0f;
  float s = 0.f;
  for (int c = 0; c < 256; c += 4){
    float4 v = *(const float4*)&row[c];
    s += v.x + v.y + v.z + v.w;
  }
  s = fmaxf(s, 1.0f);
  deg[(g<<8)+r] = s;
  pe[(size_t)((g<<8)+r)*WALKN + 0] = row[r] / s;   // diag(M^1)
}

// dense bf16 M[c][r] = A[r][c]/deg[r]  (A-operand layout [row=c][k=r])
// and Pt1[x][y] = P1^T = M^T: Pt1[x][y] = M[y][x] = A[x][y]/deg[x]
// via LDS 64x64 tile transposes (coalesced global R/W).
__global__ __launch_bounds__(256) void prep_m(const float* __restrict__ A, const float* __restrict__ deg,
                                              ushort* __restrict__ Mbf, ushort* __restrict__ Pt1){
  __shared__ float As[64][65];
  __shared__ float Bs[64][65];
  __shared__ float invd[256];
  int g = blockIdx.x;
  const float* Ag = A + ((size_t)g<<16);
  int tid = threadIdx.x, tx = tid & 63, ty = tid >> 6;
  if (tid < 256) invd[tid] = 1.f / deg[(g<<8)+tid];
  ushort* Mg = Mbf + ((size_t)g<<16);
  ushort* Pg = Pt1 + ((size_t)g<<16);
  const int pr[10] = {0,0,0,0,1,1,1,2,2,3};
  const int pc[10] = {0,1,2,3,1,2,3,2,3,3};
  for (int t = 0; t < 10; t++){
    int R0 = pr[t]*64, C0 = pc[t]*64;
    __syncthreads();
    #pragma unroll
    for (int i = 0; i < 16; i++){
      As[ty + i*4][tx] = Ag[(size_t)(R0 + ty + i*4)*256 + C0 + tx];
      Bs[ty + i*4][tx] = Ag[(size_t)(C0 + ty + i*4)*256 + R0 + tx];
    }
    __syncthreads();
    #pragma unroll
    for (int i = 0; i < 16; i++){
      int cl = ty + i*4;
      Mg[(size_t)(C0+cl)*256 + R0+tx] = f2b(As[tx][cl] * invd[R0+tx]);
      Pg[(size_t)(C0+cl)*256 + R0+tx] = f2b(Bs[cl][tx] * invd[C0+cl]);
      if (R0 != C0){
        Mg[(size_t)(R0+cl)*256 + C0+tx] = f2b(Bs[tx][cl] * invd[C0+tx]);
        Pg[(size_t)(R0+cl)*256 + C0+tx] = f2b(As[cl][tx] * invd[R0+cl]);
      }
    }
  }
}

// one dense walk step: Pout^T = (M @ Pin)^T for a 64-col slice; fp32 diag -> pe
__global__ __launch_bounds__(256, 2) void rwse_step_mf(const ushort* __restrict__ Pin,
                                                       ushort* __restrict__ Pout,
                                                       const ushort* __restrict__ Mbf,
                                                       float* __restrict__ pe, int step){
  __shared__ ushort Ma[256*40];   // 20 KB (stride 40 -> 2-way-only bank alias)
  __shared__ ushort Pb[64*40];    //  5 KB
  int g = blockIdx.x >> 2, cb = (blockIdx.x & 3) << 6;
  int tid = threadIdx.x, lane = tid & 63, w = tid >> 6;
  int l15 = lane & 15, quad = lane >> 4;
  const ushort* Mg = Mbf + ((size_t)g<<16);
  const ushort* Pg = Pin + ((size_t)g<<16);
  ffrag acc[4][4];
  #pragma unroll
  for (int m = 0; m < 4; m++)
    #pragma unroll
    for (int n = 0; n < 4; n++) acc[m][n] = (ffrag){0.f,0.f,0.f,0.f};

  for (int k0 = 0; k0 < 256; k0 += 32){
    #pragma unroll
    for (int i = 0; i < 4; i++){          // Ma: 256 rows x 32 k = 1024 uint4
      int li = tid + i*256;
      int row = li >> 2, c8 = (li & 3)*8;
      *reinterpret_cast<uint4*>(&Ma[row*40 + c8]) =
          *reinterpret_cast<const uint4*>(&Mg[(size_t)row*256 + k0 + c8]);
    }
    {                                      // Pb: 64 cols x 32 k = 256 uint4
      int col = tid >> 2, c8 = (tid & 3)*8;
      *reinterpret_cast<uint4*>(&Pb[col*40 + c8]) =
          *reinterpret_cast<const uint4*>(&Pg[(size_t)(cb+col)*256 + k0 + c8]);
    }
    __syncthreads();
    bfrag a[4], b[4];
    #pragma unroll
    for (int m = 0; m < 4; m++)
      a[m] = *reinterpret_cast<const bfrag*>(&Ma[(w*64 + m*16 + l15)*40 + quad*8]);
    #pragma unroll
    for (int n = 0; n < 4; n++)
      b[n] = *reinterpret_cast<const bfrag*>(&Pb[(n*16 + l15)*40 + quad*8]);
    #pragma unroll
    for (int m = 0; m < 4; m++)
      #pragma unroll
      for (int n = 0; n < 4; n++)
        acc[m][n] = __builtin_amdgcn_mfma_f32_16x16x32_bf16(a[m], b[n], acc[m][n], 0, 0, 0);
    __syncthreads();
  }
  // epilogue: write P^T (bf16) + fp32 diag
  ushort* Po = Pout + ((size_t)g<<16);
  #pragma unroll
  for (int m = 0; m < 4; m++){
    int rbase = w*64 + m*16 + quad*4;      // c_out rows
    #pragma unroll
    for (int n = 0; n < 4; n++){
      int col = cb + n*16 + l15;
      ushort4 pk;
      float v0 = acc[m][n][0], v1 = acc[m][n][1], v2 = acc[m][n][2], v3 = acc[m][n][3];
      pk.x = f2b(v0); pk.y = f2b(v1); pk.z = f2b(v2); pk.w = f2b(v3);
      if (col >= rbase && col < rbase+4){
        float dv = (col == rbase) ? v0 : (col == rbase+1) ? v1 : (col == rbase+2) ? v2 : v3;
        pe[(size_t)((g<<8)+col)*WALKN + step] = dv;
      }
      *reinterpret_cast<ushort4*>(&Po[(size_t)col*256 + rbase]) = pk;
    }
  }
}

// ============================================================
// concat [x | pe | 0pad] -> xin [N,64]
// ============================================================
__global__ __launch_bounds__(256) void concat_kernel(const float* __restrict__ x, const float* __restrict__ pe,
                                                     float* __restrict__ xin){
  int idx = blockIdx.x*256 + threadIdx.x;    // NN*64
  int row = idx >> 6, c = idx & 63;
  float v = 0.f;
  if (c < 30) v = x[(size_t)row*30 + c];
  else if (c < 50) v = pe[(size_t)row*20 + (c-30)];
  xin[idx] = v;
}

// ============================================================
// prep: all weights -> bf16 transposed [N][Kp] (B-operand layout)
// ============================================================
__global__ __launch_bounds__(256) void prep_wt(const float* __restrict__ in_W, const float* __restrict__ g1_W,
                                               const float* __restrict__ g2_W, const float* __restrict__ qkv_W,
                                               const float* __restrict__ o_W, const float* __restrict__ m1_W,
                                               const float* __restrict__ m2_W, ushort* __restrict__ wt){
  int rgn = blockIdx.y;
  const float* src; int K, N, Kp; size_t dst;
  if (rgn == 0){ src = in_W; K=50; N=128; Kp=64; dst = 0; }
  else if (rgn <= 3){ int i=rgn-1;  src = g1_W + (size_t)i*16384; K=128; N=128; Kp=128; dst = 8192   + (size_t)i*16384; }
  else if (rgn <= 6){ int i=rgn-4;  src = g2_W + (size_t)i*16384; K=128; N=128; Kp=128; dst = 57344  + (size_t)i*16384; }
  else if (rgn <= 9){ int i=rgn-7;  src = qkv_W+ (size_t)i*49152; K=128; N=384; Kp=128; dst = 106496 + (size_t)i*49152; }
  else if (rgn <= 12){ int i=rgn-10; src = o_W  + (size_t)i*16384; K=128; N=128; Kp=128; dst = 253952 + (size_t)i*16384; }
  else if (rgn <= 15){ int i=rgn-13; src = m1_W + (size_t)i*32768; K=128; N=256; Kp=128; dst = 303104 + (size_t)i*32768; }
  else               { int i=rgn-16; src = m2_W + (size_t)i*32768; K=256; N=128; Kp=256; dst = 401408 + (size_t)i*32768; }
  int sz = N * Kp;
  int idx = blockIdx.x*256 + threadIdx.x;
  if (idx >= sz) return;
  int n = idx / Kp, kp = idx - n*Kp;
  float v = (kp < K) ? src[(size_t)kp*N + n] : 0.f;
  wt[dst + idx] = f2b(v);
}

// ============================================================
// bf16 MFMA GEMM: Y = [BN]( [relu]( (X1[+X2]) @ W + b ) [+R] ) [+R2]
//   64-row x 128-col tile, 4 waves (2x2), wave tile 32x64, 16x16x32 bf16
// ============================================================
template<int CINP, bool RELU, bool BN, bool HAS_X2, bool HAS_R, bool HAS_R2>
__global__ __launch_bounds__(256, 2) void gemm_mf(
    const float* __restrict__ X1, const float* __restrict__ X2,
    const ushort* __restrict__ WT, const float* __restrict__ bias,
    const float* __restrict__ Rp, const float* __restrict__ R2p,
    const float* __restrict__ bng, const float* __restrict__ bnb,
    const float* __restrict__ bnm, const float* __restrict__ bnv,
    float* __restrict__ Y, int ldY, int colTiles)
{
  constexpr int KT = (CINP > 128) ? 128 : CINP;
  constexpr int XS = KT + 8;                 // LDS row stride (bf16 elems)
  __shared__ ushort XA[64 * XS];
  __shared__ ushort WS[128 * XS];
  int bt = blockIdx.x;
  int row0 = (bt / colTiles) * 64;
  int c0   = (bt % colTiles) * 128;
  int tid = threadIdx.x;
  int lane = tid & 63, wave = tid >> 6;
  int l15 = lane & 15, quad = lane >> 4;
  int wr = wave >> 1, wc = wave & 1;

  ffrag acc[2][4];
  #pragma unroll
  for (int m = 0; m < 2; m++)
    #pragma unroll
    for (int n = 0; n < 4; n++)
      acc[m][n] = (ffrag){0.f,0.f,0.f,0.f};

  #pragma unroll
  for (int s = 0; s < CINP/KT; s++){
    constexpr int F4PR = KT/4;
    #pragma unroll
    for (int it = 0; it < (64*F4PR)/256; it++){
      int idx = tid + it*256;
      int r = idx / F4PR, c4 = idx % F4PR;
      float4 v = *(const float4*)&X1[(size_t)(row0+r)*CINP + s*KT + c4*4];
      if (HAS_X2){
        float4 w = *(const float4*)&X2[(size_t)(row0+r)*CINP + s*KT + c4*4];
        v.x += w.x; v.y += w.y; v.z += w.z; v.w += w.w;
      }
      ushort4 b; b.x = f2b(v.x); b.y = f2b(v.y); b.z = f2b(v.z); b.w = f2b(v.w);
      *reinterpret_cast<ushort4*>(&XA[r*XS + c4*4]) = b;
    }
    constexpr int U4PR = KT/8;
    #pragma unroll
    for (int it = 0; it < (128*U4PR)/256; it++){
      int idx = tid + it*256;
      int n = idx / U4PR, c8 = idx % U4PR;
      uint4 v = *(const uint4*)&WT[(size_t)(c0+n)*CINP + s*KT + c8*8];
      *reinterpret_cast<uint4*>(&WS[n*XS + c8*8]) = v;
    }
    __syncthreads();
    #pragma unroll
    for (int ks = 0; ks < KT/32; ks++){
      bfrag a[2], b[4];
      #pragma unroll
      for (int m = 0; m < 2; m++)
        a[m] = *reinterpret_cast<const bfrag*>(&XA[(32*wr + 16*m + l15)*XS + ks*32 + quad*8]);
      #pragma unroll
      for (int n = 0; n < 4; n++)
        b[n] = *reinterpret_cast<const bfrag*>(&WS[(64*wc + 16*n + l15)*XS + ks*32 + quad*8]);
      #pragma unroll
      for (int m = 0; m < 2; m++)
        #pragma unroll
        for (int n = 0; n < 4; n++)
          acc[m][n] = __builtin_amdgcn_mfma_f32_16x16x32_bf16(a[m], b[n], acc[m][n], 0, 0, 0);
    }
    __syncthreads();
  }
  #pragma unroll
  for (int m = 0; m < 2; m++)
    #pragma unroll
    for (int n = 0; n < 4; n++){
      int col = c0 + 64*wc + 16*n + l15;
      float bs = bias[col];
      float bnscale = 0.f, bnsh = 0.f;
      if (BN){ bnscale = rsqrtf(bnv[col] + 1e-5f) * bng[col]; bnsh = bnb[col] - bnm[col]*bnscale; }
      #pragma unroll
      for (int rg = 0; rg < 4; rg++){
        int r = row0 + 32*wr + 16*m + quad*4 + rg;
        float v = acc[m][n][rg] + bs;
        if (RELU) v = fmaxf(v, 0.f);
        if (HAS_R) v += Rp[(size_t)r*ldY + col];
        if (BN)   v = v*bnscale + bnsh;
        if (HAS_R2) v += R2p[(size_t)r*ldY + col];
        Y[(size_t)r*ldY + col] = v;
      }
    }
}

// ============================================================
// per-layer collapsed edge weights: Wp = ep_W @ ge_W[i], bp = ep_b @ ge_W[i] + ge_b[i]
// ============================================================
__global__ __launch_bounds__(256) void wp_all(const float* __restrict__ epW, const float* __restrict__ epb,
                                              const float* __restrict__ geW, const float* __restrict__ geb,
                                              float* __restrict__ Wp, float* __restrict__ bp){
  int i = blockIdx.x;
  const float* gw = geW + (size_t)i*16384;
  float* wp = Wp + (size_t)i*1408;
  int tid = threadIdx.x;
  for (int idx = tid; idx < 1408; idx += 256){
    int t = idx >> 7, c = idx & 127;
    float s = 0.f;
    for (int k = 0; k < 128; k++) s += epW[t*128+k] * gw[(size_t)k*128 + c];
    wp[idx] = s;
  }
  if (tid < 128){
    float s = geb[(size_t)i*128 + tid];
    for (int k = 0; k < 128; k++) s += epb[k] * gw[(size_t)k*128 + tid];
    bp[(size_t)i*128 + tid] = s;
  }
}

// ============================================================
// GINE aggregation (dst-CSR): aggr[n] = sum_e relu(h[src]+edge_attr[e]@Wp+bp)
// ============================================================
__global__ __launch_bounds__(256) void gine_aggr(const float* __restrict__ h, const float* __restrict__ ea,
                                                 const int* __restrict__ ei, const int* __restrict__ Ecsr,
                                                 const int* __restrict__ Ecnt,
                                                 const float* __restrict__ Wp, const float* __restrict__ bp,
                                                 float* __restrict__ aggr){
  int n = blockIdx.x*2 + (threadIdx.x >> 7);
  int ch = threadIdx.x & 127;
  int cnt = Ecnt[n]; if (cnt > 64) cnt = 64;
  float wreg[11];
  #pragma unroll
  for (int t = 0; t < 11; t++) wreg[t] = Wp[t*128 + ch];
  float bpc = bp[ch];
  float acc = 0.f;
  for (int j = 0; j < cnt; j++){
    int e = Ecsr[((size_t)n<<6) + j];
    int s = ei[e];
    const float* eap = ea + (size_t)e*11;
    float v = bpc;
    #pragma unroll
    for (int t = 0; t < 11; t++) v += eap[t] * wreg[t];
    v += h[(size_t)s*128 + ch];
    acc += fmaxf(v, 0.f);
  }
  aggr[(size_t)n*128 + ch] = acc;
}

// ============================================================
// MFMA attention: block per (graph, head); 4 waves, wave = 64 q rows
// ============================================================
__global__ __launch_bounds__(256, 2) void attn_mf(const float* __restrict__ qkv, float* __restrict__ o){
  __shared__ ushort Ks[256 * 40];        // K  [key][d]   20.5 KB
  __shared__ ushort Vt[32 * 264];        // V^T [d][key]  16.9 KB
  __shared__ ushort PA[4 * 16 * 264];    // P per wave [q][key] 33.8 KB
  int g = blockIdx.x >> 2, hh = blockIdx.x & 3;
  int tid = threadIdx.x, lane = tid & 63, w = tid >> 6;
  int l15 = lane & 15, quad = lane >> 4;
  const float* base = qkv + (size_t)(g<<8)*384;

  #pragma unroll
  for (int it = 0; it < 8; it++){
    int idx = tid + it*256;              // 2048 float4 over 256x32
    int key = idx >> 3, d4 = idx & 7;
    float4 kv = *(const float4*)&base[(size_t)key*384 + 128 + hh*32 + d4*4];
    ushort4 kb; kb.x=f2b(kv.x); kb.y=f2b(kv.y); kb.z=f2b(kv.z); kb.w=f2b(kv.w);
    *reinterpret_cast<ushort4*>(&Ks[key*40 + d4*4]) = kb;
    float4 vv = *(const float4*)&base[(size_t)key*384 + 256 + hh*32 + d4*4];
    Vt[(d4*4+0)*264 + key] = f2b(vv.x);
    Vt[(d4*4+1)*264 + key] = f2b(vv.y);
    Vt[(d4*4+2)*264 + key] = f2b(vv.z);
    Vt[(d4*4+3)*264 + key] = f2b(vv.w);
  }
  bfrag qf[4];
  #pragma unroll
  for (int qg = 0; qg < 4; qg++){
    int q = w*64 + qg*16 + l15;
    const float* qp = base + (size_t)q*384 + hh*32 + quad*8;
    float4 v0 = *(const float4*)qp;
    float4 v1 = *(const float4*)(qp + 4);
    bfrag t;
    t[0]=(short)f2b(v0.x); t[1]=(short)f2b(v0.y); t[2]=(short)f2b(v0.z); t[3]=(short)f2b(v0.w);
    t[4]=(short)f2b(v1.x); t[5]=(short)f2b(v1.y); t[6]=(short)f2b(v1.z); t[7]=(short)f2b(v1.w);
    qf[qg] = t;
  }
  __syncthreads();

  ushort* pw = &PA[w * 16 * 264];
  const float sc_ = 0.17677669529663687f;   // 32^-0.5
  for (int qg = 0; qg < 4; qg++){
    ffrag sc[16];
    #pragma unroll
    for (int kg = 0; kg < 16; kg++){
      bfrag bk = *reinterpret_cast<const bfrag*>(&Ks[(kg*16 + l15)*40 + quad*8]);
      ffrag z = (ffrag){0.f,0.f,0.f,0.f};
      sc[kg] = __builtin_amdgcn_mfma_f32_16x16x32_bf16(qf[qg], bk, z, 0, 0, 0);
    }
    float inv_l[4];
    #pragma unroll
    for (int rg = 0; rg < 4; rg++){
      float m = sc[0][rg];
      #pragma unroll
      for (int kg = 1; kg < 16; kg++) m = fmaxf(m, sc[kg][rg]);
      #pragma unroll
      for (int off = 1; off < 16; off <<= 1) m = fmaxf(m, __shfl_xor(m, off, 16));
      float ssum = 0.f;
      #pragma unroll
      for (int kg = 0; kg < 16; kg++){
        float p = __expf((sc[kg][rg] - m) * sc_);
        sc[kg][rg] = p; ssum += p;
      }
      #pragma unroll
      for (int off = 1; off < 16; off <<= 1) ssum += __shfl_xor(ssum, off, 16);
      inv_l[rg] = 1.f / ssum;
    }
    #pragma unroll
    for (int kg = 0; kg < 16; kg++)
      #pragma unroll
      for (int rg = 0; rg < 4; rg++)
        pw[(quad*4 + rg)*264 + kg*16 + l15] = f2b(sc[kg][rg]);
    ffrag oa[2];
    oa[0] = (ffrag){0.f,0.f,0.f,0.f};
    oa[1] = (ffrag){0.f,0.f,0.f,0.f};
    #pragma unroll
    for (int ks = 0; ks < 8; ks++){
      bfrag pa = *reinterpret_cast<const bfrag*>(&pw[l15*264 + ks*32 + quad*8]);
      #pragma unroll
      for (int n16 = 0; n16 < 2; n16++){
        bfrag bv = *reinterpret_cast<const bfrag*>(&Vt[(n16*16 + l15)*264 + ks*32 + quad*8]);
        oa[n16] = __builtin_amdgcn_mfma_f32_16x16x32_bf16(pa, bv, oa[n16], 0, 0, 0);
      }
    }
    #pragma unroll
    for (int n16 = 0; n16 < 2; n16++)
      #pragma unroll
      for (int rg = 0; rg < 4; rg++){
        int q = w*64 + qg*16 + quad*4 + rg;
        int col = hh*32 + n16*16 + l15;
        o[((size_t)(g<<8) + q)*128 + col] = oa[n16][rg] * inv_l[rg];
      }
  }
}

// ============================================================
// mean-pool + 2-layer head
// ============================================================
__global__ __launch_bounds__(256) void head_kernel(const float* __restrict__ h,
                                                   const float* __restrict__ W1, const float* __restrict__ b1,
                                                   const float* __restrict__ W2, const float* __restrict__ b2,
                                                   float* __restrict__ out){
  int g = blockIdx.x, tid = threadIdx.x;
  int c = tid & 127, half = tid >> 7;
  __shared__ float part[2][128];
  __shared__ float pool[128];
  __shared__ float hid[64];
  float s = 0.f;
  for (int n = half*128; n < half*128 + 128; n++)
    s += h[(size_t)((g<<8)+n)*128 + c];
  part[half][c] = s;
  __syncthreads();
  if (tid < 128) pool[tid] = (part[0][tid] + part[1][tid]) * (1.f/256.f);
  __syncthreads();
  if (tid < 64){
    float v = b1[tid];
    for (int k = 0; k < 128; k++) v += pool[k] * W1[k*64 + tid];
    hid[tid] = fmaxf(v, 0.f);
  }
  __syncthreads();
  if (tid == 0){
    float v = b2[0];
    for (int k = 0; k < 64; k++) v += hid[k] * W2[k];
    out[g] = v;
  }
}

// ============================================================
extern "C" void kernel_launch(void* const* d_in, const int* in_sizes, int n_in,
                              void* d_out, int out_size, void* d_ws, size_t ws_size,
                              hipStream_t stream){
  (void)in_sizes; (void)n_in; (void)out_size; (void)ws_size;
  const float* x      = (const float*)d_in[0];
  const float* eattr  = (const float*)d_in[1];
  const float* in_W   = (const float*)d_in[2];
  const float* in_b   = (const float*)d_in[3];
  const float* ep_W   = (const float*)d_in[4];
  const float* ep_b   = (const float*)d_in[5];
  const float* ge_W   = (const float*)d_in[6];
  const float* ge_b   = (const float*)d_in[7];
  const float* g1_W   = (const float*)d_in[8];
  const float* g1_b   = (const float*)d_in[9];
  const float* g2_W   = (const float*)d_in[10];
  const float* g2_b   = (const float*)d_in[11];
  const float* qkv_W  = (const float*)d_in[12];
  const float* qkv_b  = (const float*)d_in[13];
  const float* o_W    = (const float*)d_in[14];
  const float* o_b    = (const float*)d_in[15];
  const float* bn1g = (const float*)d_in[16]; const float* bn1b = (const float*)d_in[17];
  const float* bn1m = (const float*)d_in[18]; const float* bn1v = (const float*)d_in[19];
  const float* bn2g = (const float*)d_in[20]; const float* bn2b = (const float*)d_in[21];
  const float* bn2m = (const float*)d_in[22]; const float* bn2v = (const float*)d_in[23];
  const float* bn3g = (const float*)d_in[24]; const float* bn3b = (const float*)d_in[25];
  const float* bn3m = (const float*)d_in[26]; const float* bn3v = (const float*)d_in[27];
  const float* m1_W = (const float*)d_in[28]; const float* m1_b = (const float*)d_in[29];
  const float* m2_W = (const float*)d_in[30]; const float* m2_b = (const float*)d_in[31];
  const float* h1_W = (const float*)d_in[32]; const float* h1_b = (const float*)d_in[33];
  const float* h2_W = (const float*)d_in[34]; const float* h2_b = (const float*)d_in[35];
  const int*   ei   = (const int*)d_in[36];
  float* out = (float*)d_out;
  float* ws  = (float*)d_ws;
  int*   wsi = (int*)d_ws;

  // ---- workspace layout (fp32-element offsets) ----
  // RWSE-phase region (dead after rwse steps):
  const size_t oA    = 0;            // 8,388,608 fp32 (dense A)
  const size_t oMbf  = 8388608;      // 8.4M ushort = 4,194,304 slots
  const size_t oPtA  = 12582912;     // 8.4M ushort = 4,194,304 slots
  const size_t oPtB  = 16777216;     // 8.4M ushort = 4,194,304 slots (ends 20,971,520)
  // overlays (post-RWSE):
  const size_t oXin  = 0;            // NN*64 = 2,097,152
  const size_t oQKV  = 0;            // 12,582,912
  const size_t oT2   = 12582912;     // 8,388,608
  const size_t oOB   = 20971520;     // 4,194,304   (ends 25,165,824)
  // persistent:
  const size_t oDeg  = 25165824;     // 32,768
  const size_t oPe   = 25198592;     // 655,360
  const size_t oH    = 25853952;     // 4,194,304
  const size_t oAg   = 30048256;     // 4,194,304
  const size_t oT1   = 34242560;     // 4,194,304
  const size_t oH1   = 38436864;     // 4,194,304
  const size_t oOut  = 42631168;     // 4,194,304
  const size_t oWp   = 46825472;     // 4,224
  const size_t oBp   = 46829696;     // 384
  const size_t oEcsr = 46830080;     // 2,097,152 int
  const size_t oEcnt = 48927232;     // 32,768 int
  const size_t oWT   = 48960000;     // 499,712 ushort = 249,856 fp32 slots
  ushort* wt  = (ushort*)(ws + oWT);
  ushort* mbf = (ushort*)(ws + oMbf);
  ushort* ptA = (ushort*)(ws + oPtA);
  ushort* ptB = (ushort*)(ws + oPtB);

  // ---- RWSE (dense MFMA path) ----
  hipMemsetAsync(ws + oA, 0, 8388608*sizeof(float), stream);
  hipMemsetAsync(wsi + oEcnt, 0, 32768*sizeof(int), stream);
  build_edges<<<NEDGE/256, 256, 0, stream>>>(ei, ws+oA, wsi+oEcsr, wsi+oEcnt);
  rwse_deg<<<GN, 256, 0, stream>>>(ws+oA, ws+oDeg, ws+oPe);
  prep_m<<<GN, 256, 0, stream>>>(ws+oA, ws+oDeg, mbf, ptA);
  ushort* pt[2] = { ptA, ptB };
  for (int s = 1; s < WALKN; s++)
    rwse_step_mf<<<GN*4, 256, 0, stream>>>(pt[(s-1)&1], pt[s&1], mbf, ws+oPe, s);

  // ---- weight prep (bf16 transposed) ----
  prep_wt<<<dim3(192, 19), 256, 0, stream>>>(in_W, g1_W, g2_W, qkv_W, o_W, m1_W, m2_W, wt);

  // ---- input proj ----
  concat_kernel<<<NN*64/256, 256, 0, stream>>>(x, ws+oPe, ws+oXin);
  gemm_mf<64,false,false,false,false,false><<<512, 256, 0, stream>>>(
      ws+oXin, nullptr, wt + 0, in_b, nullptr, nullptr, nullptr, nullptr, nullptr, nullptr,
      ws+oH, 128, 1);

  wp_all<<<3, 256, 0, stream>>>(ep_W, ep_b, ge_W, ge_b, ws+oWp, ws+oBp);

  // ---- layers ----
  for (int i = 0; i < 3; i++){
    gine_aggr<<<NN/2, 256, 0, stream>>>(ws+oH, eattr, ei, wsi+oEcsr, wsi+oEcnt,
                                        ws+oWp + (size_t)i*1408, ws+oBp + (size_t)i*128, ws+oAg);
    gemm_mf<128,true,false,true,false,false><<<512, 256, 0, stream>>>(
        ws+oH, ws+oAg, wt + 8192 + (size_t)i*16384, g1_b + (size_t)i*128,
        nullptr, nullptr, nullptr, nullptr, nullptr, nullptr, ws+oT1, 128, 1);
    gemm_mf<128,false,true,false,true,false><<<512, 256, 0, stream>>>(
        ws+oT1, nullptr, wt + 57344 + (size_t)i*16384, g2_b + (size_t)i*128,
        ws+oH, nullptr, bn1g+(size_t)i*128, bn1b+(size_t)i*128, bn1m+(size_t)i*128, bn1v+(size_t)i*128,
        ws+oH1, 128, 1);
    gemm_mf<128,false,false,false,false,false><<<1536, 256, 0, stream>>>(
        ws+oH, nullptr, wt + 106496 + (size_t)i*49152, qkv_b + (size_t)i*384,
        nullptr, nullptr, nullptr, nullptr, nullptr, nullptr, ws+oQKV, 384, 3);
    attn_mf<<<GN*4, 256, 0, stream>>>(ws+oQKV, ws+oOB);
    gemm_mf<128,false,true,false,true,true><<<512, 256, 0, stream>>>(
        ws+oOB, nullptr, wt + 253952 + (size_t)i*16384, o_b + (size_t)i*128,
        ws+oH, ws+oH1, bn2g+(size_t)i*128, bn2b+(size_t)i*128, bn2m+(size_t)i*128, bn2v+(size_t)i*128,
        ws+oOut, 128, 1);
    gemm_mf<128,true,false,false,false,false><<<1024, 256, 0, stream>>>(
        ws+oOut, nullptr, wt + 303104 + (size_t)i*32768, m1_b + (size_t)i*256,
        nullptr, nullptr, nullptr, nullptr, nullptr, nullptr, ws+oT2, 256, 2);
    gemm_mf<256,false,true,false,true,false><<<512, 256, 0, stream>>>(
        ws+oT2, nullptr, wt + 401408 + (size_t)i*32768, m2_b + (size_t)i*128,
        ws+oOut, nullptr, bn3g+(size_t)i*128, bn3b+(size_t)i*128, bn3m+(size_t)i*128, bn3v+(size_t)i*128,
        ws+oH, 128, 1);
  }

  head_kernel<<<GN, 256, 0, stream>>>(ws+oH, h1_W, h1_b, h2_W, h2_b, out);
}

// Round 5
// 825.303 us; speedup vs baseline: 4.3635x; 1.5549x over previous
//
#include <hip/hip_runtime.h>

#define GN   128      // graphs
#define GP   256      // nodes per graph
#define NN   32768    // total nodes
#define NEDGE 262144  // total edges
#define WALKN 20

typedef __attribute__((ext_vector_type(8))) short bfrag;   // 8 bf16 (4 VGPRs)
typedef __attribute__((ext_vector_type(4))) float ffrag;   // 4 fp32 acc

__device__ __forceinline__ ushort f2b(float f){
  unsigned u = __float_as_uint(f);
  u += 0x7fffu + ((u >> 16) & 1u);      // RNE
  return (ushort)(u >> 16);
}

// ============================================================
// build A (dense counts) + per-edge dst slot
// ============================================================
__global__ __launch_bounds__(256) void build_edges(const int* __restrict__ ei, float* __restrict__ A,
                                                   int* __restrict__ epos, int* __restrict__ Ecnt){
  int e = blockIdx.x*256 + threadIdx.x;
  int s = ei[e], d = ei[NEDGE + e];
  int g = s >> 8;
  atomicAdd(&A[((size_t)g<<16) + ((size_t)(s&255)<<8) + (size_t)(d&255)], 1.0f);
  epos[e] = atomicAdd(&Ecnt[d], 1);
}

// pack {src, ea[0..10]} grouped by dst (48B records, 32 slots/node)
__global__ __launch_bounds__(256) void pack_edges(const int* __restrict__ ei, const float* __restrict__ ea,
                                                  const int* __restrict__ epos, float* __restrict__ pk){
  int e = blockIdx.x*256 + threadIdx.x;
  int d = ei[NEDGE + e];
  int pos = epos[e];
  if (pos >= 32) return;
  float* dst = pk + ((size_t)d*32 + pos)*12;
  dst[0] = __int_as_float(ei[e]);
  const float* s = ea + (size_t)e*11;
  #pragma unroll
  for (int t = 0; t < 11; t++) dst[1+t] = s[t];
}

// add self loops + out-degree (row sums, clipped >=1)
__global__ __launch_bounds__(256) void rwse_deg(float* __restrict__ A, float* __restrict__ deg){
  int g = blockIdx.x, r = threadIdx.x;
  float* row = A + ((size_t)g<<16) + ((size_t)r<<8);
  row[r] += 1.0f;
  float s = 0.f;
  for (int c = 0; c < 256; c += 4){
    float4 v = *(const float4*)&row[c];
    s += v.x + v.y + v.z + v.w;
  }
  deg[(g<<8)+r] = fmaxf(s, 1.0f);
}

// dense bf16 M[c][r] = A[r][c]/deg[r]  (MFMA A-operand layout [row=c][k=r])
__global__ __launch_bounds__(256) void prep_m(const float* __restrict__ A, const float* __restrict__ deg,
                                              ushort* __restrict__ Mbf){
  __shared__ float As[64][65];
  __shared__ float Bs[64][65];
  __shared__ float invd[256];
  int g = blockIdx.x;
  const float* Ag = A + ((size_t)g<<16);
  int tid = threadIdx.x, tx = tid & 63, ty = tid >> 6;
  invd[tid] = 1.f / deg[(g<<8)+tid];
  ushort* Mg = Mbf + ((size_t)g<<16);
  const int pr[10] = {0,0,0,0,1,1,1,2,2,3};
  const int pc[10] = {0,1,2,3,1,2,3,2,3,3};
  for (int t = 0; t < 10; t++){
    int R0 = pr[t]*64, C0 = pc[t]*64;
    __syncthreads();
    #pragma unroll
    for (int i = 0; i < 16; i++){
      As[ty + i*4][tx] = Ag[(size_t)(R0 + ty + i*4)*256 + C0 + tx];
      Bs[ty + i*4][tx] = Ag[(size_t)(C0 + ty + i*4)*256 + R0 + tx];
    }
    __syncthreads();
    #pragma unroll
    for (int i = 0; i < 16; i++){
      int cl = ty + i*4;
      Mg[(size_t)(C0+cl)*256 + R0+tx] = f2b(As[tx][cl] * invd[R0+tx]);
      if (R0 != C0)
        Mg[(size_t)(R0+cl)*256 + C0+tx] = f2b(Bs[tx][cl] * invd[C0+tx]);
    }
  }
}

// ============================================================
// ALL 20 walk steps in one kernel. Block owns a 64-col slice of P for its
// graph; P^T (bf16) stays in LDS across steps; M read from global (L2-
// resident via XCD swizzle: all 4 slices of a graph + 16 graphs per XCD).
// ============================================================
__global__ __launch_bounds__(256, 2) void rwse_mf(const ushort* __restrict__ Mbf,
                                                  float* __restrict__ pe){
  __shared__ __align__(16) ushort Pt[64*264];   // [col][row], 33.8 KB
  int bid = blockIdx.x;
  int g  = (bid & 7)*16 + (bid >> 5);           // XCD-local graph grouping
  int cb = ((bid >> 3) & 3) << 6;
  int tid = threadIdx.x, lane = tid & 63, w = tid >> 6;
  int l15 = lane & 15, quad = lane >> 4;
  const ushort* Mg = Mbf + ((size_t)g << 16);
  // init Pt = I-slice
  uint4 z4; z4.x = z4.y = z4.z = z4.w = 0u;
  for (int i = tid; i < 2112; i += 256) reinterpret_cast<uint4*>(Pt)[i] = z4;
  __syncthreads();
  if (tid < 64) Pt[tid*264 + cb + tid] = 0x3F80;   // 1.0bf16
  __syncthreads();

  for (int s = 0; s < WALKN; s++){
    ffrag acc[4][4];
    #pragma unroll
    for (int mi = 0; mi < 4; mi++)
      #pragma unroll
      for (int n = 0; n < 4; n++) acc[mi][n] = (ffrag){0.f,0.f,0.f,0.f};
    for (int k0 = 0; k0 < 256; k0 += 32){
      bfrag a[4], b[4];
      #pragma unroll
      for (int mi = 0; mi < 4; mi++)
        a[mi] = *reinterpret_cast<const bfrag*>(&Mg[(size_t)(w*64 + mi*16 + l15)*256 + k0 + quad*8]);
      #pragma unroll
      for (int n = 0; n < 4; n++)
        b[n] = *reinterpret_cast<const bfrag*>(&Pt[(n*16 + l15)*264 + k0 + quad*8]);
      #pragma unroll
      for (int mi = 0; mi < 4; mi++)
        #pragma unroll
        for (int n = 0; n < 4; n++)
          acc[mi][n] = __builtin_amdgcn_mfma_f32_16x16x32_bf16(a[mi], b[n], acc[mi][n], 0, 0, 0);
    }
    __syncthreads();                  // all reads of Pt done
    #pragma unroll
    for (int mi = 0; mi < 4; mi++){
      int rbase = w*64 + mi*16 + quad*4;
      #pragma unroll
      for (int n = 0; n < 4; n++){
        int cl = n*16 + l15;
        int dd = cb + cl - rbase;
        if (dd >= 0 && dd < 4){       // fp32 diag before rounding
          float dv = (dd==0)?acc[mi][n][0]:(dd==1)?acc[mi][n][1]:(dd==2)?acc[mi][n][2]:acc[mi][n][3];
          pe[(size_t)((g<<8) + cb + cl)*WALKN + s] = dv;
        }
        ushort4 pkk;
        pkk.x = f2b(acc[mi][n][0]); pkk.y = f2b(acc[mi][n][1]);
        pkk.z = f2b(acc[mi][n][2]); pkk.w = f2b(acc[mi][n][3]);
        *reinterpret_cast<ushort4*>(&Pt[cl*264 + rbase]) = pkk;
      }
    }
    __syncthreads();                  // writes visible before next step
  }
}

// ============================================================
// concat [x | pe | 0pad] -> xin [N,64]
// ============================================================
__global__ __launch_bounds__(256) void concat_kernel(const float* __restrict__ x, const float* __restrict__ pe,
                                                     float* __restrict__ xin){
  int idx = blockIdx.x*256 + threadIdx.x;    // NN*64
  int row = idx >> 6, c = idx & 63;
  float v = 0.f;
  if (c < 30) v = x[(size_t)row*30 + c];
  else if (c < 50) v = pe[(size_t)row*20 + (c-30)];
  xin[idx] = v;
}

// ============================================================
// prep: all weights -> bf16 transposed [N][Kp] (B-operand layout)
// ============================================================
__global__ __launch_bounds__(256) void prep_wt(const float* __restrict__ in_W, const float* __restrict__ g1_W,
                                               const float* __restrict__ g2_W, const float* __restrict__ qkv_W,
                                               const float* __restrict__ o_W, const float* __restrict__ m1_W,
                                               const float* __restrict__ m2_W, ushort* __restrict__ wt){
  int rgn = blockIdx.y;
  const float* src; int K, N, Kp; size_t dst;
  if (rgn == 0){ src = in_W; K=50; N=128; Kp=64; dst = 0; }
  else if (rgn <= 3){ int i=rgn-1;  src = g1_W + (size_t)i*16384; K=128; N=128; Kp=128; dst = 8192   + (size_t)i*16384; }
  else if (rgn <= 6){ int i=rgn-4;  src = g2_W + (size_t)i*16384; K=128; N=128; Kp=128; dst = 57344  + (size_t)i*16384; }
  else if (rgn <= 9){ int i=rgn-7;  src = qkv_W+ (size_t)i*49152; K=128; N=384; Kp=128; dst = 106496 + (size_t)i*49152; }
  else if (rgn <= 12){ int i=rgn-10; src = o_W  + (size_t)i*16384; K=128; N=128; Kp=128; dst = 253952 + (size_t)i*16384; }
  else if (rgn <= 15){ int i=rgn-13; src = m1_W + (size_t)i*32768; K=128; N=256; Kp=128; dst = 303104 + (size_t)i*32768; }
  else               { int i=rgn-16; src = m2_W + (size_t)i*32768; K=256; N=128; Kp=256; dst = 401408 + (size_t)i*32768; }
  int sz = N * Kp;
  int idx = blockIdx.x*256 + threadIdx.x;
  if (idx >= sz) return;
  int n = idx / Kp, kp = idx - n*Kp;
  float v = (kp < K) ? src[(size_t)kp*N + n] : 0.f;
  wt[dst + idx] = f2b(v);
}

// ============================================================
// bf16 MFMA GEMM: Y = [BN]( [relu]( (X1[+X2]) @ W + b ) [+R] ) [+R2]
// ============================================================
template<int CINP, bool RELU, bool BN, bool HAS_X2, bool HAS_R, bool HAS_R2>
__global__ __launch_bounds__(256, 2) void gemm_mf(
    const float* __restrict__ X1, const float* __restrict__ X2,
    const ushort* __restrict__ WT, const float* __restrict__ bias,
    const float* __restrict__ Rp, const float* __restrict__ R2p,
    const float* __restrict__ bng, const float* __restrict__ bnb,
    const float* __restrict__ bnm, const float* __restrict__ bnv,
    float* __restrict__ Y, int ldY, int colTiles)
{
  constexpr int KT = (CINP > 128) ? 128 : CINP;
  constexpr int XS = KT + 8;
  __shared__ ushort XA[64 * XS];
  __shared__ ushort WS[128 * XS];
  int bt = blockIdx.x;
  int row0 = (bt / colTiles) * 64;
  int c0   = (bt % colTiles) * 128;
  int tid = threadIdx.x;
  int lane = tid & 63, wave = tid >> 6;
  int l15 = lane & 15, quad = lane >> 4;
  int wr = wave >> 1, wc = wave & 1;

  ffrag acc[2][4];
  #pragma unroll
  for (int m = 0; m < 2; m++)
    #pragma unroll
    for (int n = 0; n < 4; n++)
      acc[m][n] = (ffrag){0.f,0.f,0.f,0.f};

  #pragma unroll
  for (int s = 0; s < CINP/KT; s++){
    constexpr int F4PR = KT/4;
    #pragma unroll
    for (int it = 0; it < (64*F4PR)/256; it++){
      int idx = tid + it*256;
      int r = idx / F4PR, c4 = idx % F4PR;
      float4 v = *(const float4*)&X1[(size_t)(row0+r)*CINP + s*KT + c4*4];
      if (HAS_X2){
        float4 w = *(const float4*)&X2[(size_t)(row0+r)*CINP + s*KT + c4*4];
        v.x += w.x; v.y += w.y; v.z += w.z; v.w += w.w;
      }
      ushort4 b; b.x = f2b(v.x); b.y = f2b(v.y); b.z = f2b(v.z); b.w = f2b(v.w);
      *reinterpret_cast<ushort4*>(&XA[r*XS + c4*4]) = b;
    }
    constexpr int U4PR = KT/8;
    #pragma unroll
    for (int it = 0; it < (128*U4PR)/256; it++){
      int idx = tid + it*256;
      int n = idx / U4PR, c8 = idx % U4PR;
      uint4 v = *(const uint4*)&WT[(size_t)(c0+n)*CINP + s*KT + c8*8];
      *reinterpret_cast<uint4*>(&WS[n*XS + c8*8]) = v;
    }
    __syncthreads();
    #pragma unroll
    for (int ks = 0; ks < KT/32; ks++){
      bfrag a[2], b[4];
      #pragma unroll
      for (int m = 0; m < 2; m++)
        a[m] = *reinterpret_cast<const bfrag*>(&XA[(32*wr + 16*m + l15)*XS + ks*32 + quad*8]);
      #pragma unroll
      for (int n = 0; n < 4; n++)
        b[n] = *reinterpret_cast<const bfrag*>(&WS[(64*wc + 16*n + l15)*XS + ks*32 + quad*8]);
      #pragma unroll
      for (int m = 0; m < 2; m++)
        #pragma unroll
        for (int n = 0; n < 4; n++)
          acc[m][n] = __builtin_amdgcn_mfma_f32_16x16x32_bf16(a[m], b[n], acc[m][n], 0, 0, 0);
    }
    __syncthreads();
  }
  #pragma unroll
  for (int m = 0; m < 2; m++)
    #pragma unroll
    for (int n = 0; n < 4; n++){
      int col = c0 + 64*wc + 16*n + l15;
      float bs = bias[col];
      float bnscale = 0.f, bnsh = 0.f;
      if (BN){ bnscale = rsqrtf(bnv[col] + 1e-5f) * bng[col]; bnsh = bnb[col] - bnm[col]*bnscale; }
      #pragma unroll
      for (int rg = 0; rg < 4; rg++){
        int r = row0 + 32*wr + 16*m + quad*4 + rg;
        float v = acc[m][n][rg] + bs;
        if (RELU) v = fmaxf(v, 0.f);
        if (HAS_R) v += Rp[(size_t)r*ldY + col];
        if (BN)   v = v*bnscale + bnsh;
        if (HAS_R2) v += R2p[(size_t)r*ldY + col];
        Y[(size_t)r*ldY + col] = v;
      }
    }
}

// ============================================================
// per-layer collapsed edge weights
// ============================================================
__global__ __launch_bounds__(256) void wp_all(const float* __restrict__ epW, const float* __restrict__ epb,
                                              const float* __restrict__ geW, const float* __restrict__ geb,
                                              float* __restrict__ Wp, float* __restrict__ bp){
  int i = blockIdx.x;
  const float* gw = geW + (size_t)i*16384;
  float* wp = Wp + (size_t)i*1408;
  int tid = threadIdx.x;
  for (int idx = tid; idx < 1408; idx += 256){
    int t = idx >> 7, c = idx & 127;
    float s = 0.f;
    for (int k = 0; k < 128; k++) s += epW[t*128+k] * gw[(size_t)k*128 + c];
    wp[idx] = s;
  }
  if (tid < 128){
    float s = geb[(size_t)i*128 + tid];
    for (int k = 0; k < 128; k++) s += epb[k] * gw[(size_t)k*128 + tid];
    bp[(size_t)i*128 + tid] = s;
  }
}

// ============================================================
// GINE aggregation from packed per-dst records: 4-wide MLP
// ============================================================
__global__ __launch_bounds__(256) void gine_aggr2(const float* __restrict__ h, const float* __restrict__ pk,
                                                  const int* __restrict__ Ecnt,
                                                  const float* __restrict__ Wp, const float* __restrict__ bp,
                                                  float* __restrict__ aggr){
  int n = blockIdx.x*2 + (threadIdx.x >> 7);
  int ch = threadIdx.x & 127;
  int cnt = Ecnt[n]; if (cnt > 32) cnt = 32;
  float wreg[11];
  #pragma unroll
  for (int t = 0; t < 11; t++) wreg[t] = Wp[t*128 + ch];
  float bpc = bp[ch];
  const float* pkn = pk + (size_t)n*384;
  float acc = 0.f;
  int j = 0;
  for (; j + 4 <= cnt; j += 4){
    const float* p0 = pkn + (size_t)(j+0)*12;
    const float* p1 = pkn + (size_t)(j+1)*12;
    const float* p2 = pkn + (size_t)(j+2)*12;
    const float* p3 = pkn + (size_t)(j+3)*12;
    int s0 = __float_as_int(p0[0]), s1 = __float_as_int(p1[0]);
    int s2 = __float_as_int(p2[0]), s3 = __float_as_int(p3[0]);
    float h0 = h[(size_t)s0*128 + ch];
    float h1 = h[(size_t)s1*128 + ch];
    float h2 = h[(size_t)s2*128 + ch];
    float h3 = h[(size_t)s3*128 + ch];
    float e0 = bpc, e1 = bpc, e2 = bpc, e3 = bpc;
    #pragma unroll
    for (int t = 0; t < 11; t++){
      e0 += p0[1+t]*wreg[t]; e1 += p1[1+t]*wreg[t];
      e2 += p2[1+t]*wreg[t]; e3 += p3[1+t]*wreg[t];
    }
    acc += fmaxf(h0+e0, 0.f) + fmaxf(h1+e1, 0.f) + fmaxf(h2+e2, 0.f) + fmaxf(h3+e3, 0.f);
  }
  for (; j < cnt; j++){
    const float* p0 = pkn + (size_t)j*12;
    int s0 = __float_as_int(p0[0]);
    float h0 = h[(size_t)s0*128 + ch];
    float e0 = bpc;
    #pragma unroll
    for (int t = 0; t < 11; t++) e0 += p0[1+t]*wreg[t];
    acc += fmaxf(h0+e0, 0.f);
  }
  aggr[(size_t)n*128 + ch] = acc;
}

// ============================================================
// MFMA attention: block per (graph, head)
// ============================================================
__global__ __launch_bounds__(256, 2) void attn_mf(const float* __restrict__ qkv, float* __restrict__ o){
  __shared__ ushort Ks[256 * 40];
  __shared__ ushort Vt[32 * 264];
  __shared__ ushort PA[4 * 16 * 264];
  int g = blockIdx.x >> 2, hh = blockIdx.x & 3;
  int tid = threadIdx.x, lane = tid & 63, w = tid >> 6;
  int l15 = lane & 15, quad = lane >> 4;
  const float* base = qkv + (size_t)(g<<8)*384;

  #pragma unroll
  for (int it = 0; it < 8; it++){
    int idx = tid + it*256;
    int key = idx >> 3, d4 = idx & 7;
    float4 kv = *(const float4*)&base[(size_t)key*384 + 128 + hh*32 + d4*4];
    ushort4 kb; kb.x=f2b(kv.x); kb.y=f2b(kv.y); kb.z=f2b(kv.z); kb.w=f2b(kv.w);
    *reinterpret_cast<ushort4*>(&Ks[key*40 + d4*4]) = kb;
    float4 vv = *(const float4*)&base[(size_t)key*384 + 256 + hh*32 + d4*4];
    Vt[(d4*4+0)*264 + key] = f2b(vv.x);
    Vt[(d4*4+1)*264 + key] = f2b(vv.y);
    Vt[(d4*4+2)*264 + key] = f2b(vv.z);
    Vt[(d4*4+3)*264 + key] = f2b(vv.w);
  }
  bfrag qf[4];
  #pragma unroll
  for (int qg = 0; qg < 4; qg++){
    int q = w*64 + qg*16 + l15;
    const float* qp = base + (size_t)q*384 + hh*32 + quad*8;
    float4 v0 = *(const float4*)qp;
    float4 v1 = *(const float4*)(qp + 4);
    bfrag t;
    t[0]=(short)f2b(v0.x); t[1]=(short)f2b(v0.y); t[2]=(short)f2b(v0.z); t[3]=(short)f2b(v0.w);
    t[4]=(short)f2b(v1.x); t[5]=(short)f2b(v1.y); t[6]=(short)f2b(v1.z); t[7]=(short)f2b(v1.w);
    qf[qg] = t;
  }
  __syncthreads();

  ushort* pw = &PA[w * 16 * 264];
  const float sc_ = 0.17677669529663687f;
  for (int qg = 0; qg < 4; qg++){
    ffrag sc[16];
    #pragma unroll
    for (int kg = 0; kg < 16; kg++){
      bfrag bk = *reinterpret_cast<const bfrag*>(&Ks[(kg*16 + l15)*40 + quad*8]);
      ffrag z = (ffrag){0.f,0.f,0.f,0.f};
      sc[kg] = __builtin_amdgcn_mfma_f32_16x16x32_bf16(qf[qg], bk, z, 0, 0, 0);
    }
    float inv_l[4];
    #pragma unroll
    for (int rg = 0; rg < 4; rg++){
      float m = sc[0][rg];
      #pragma unroll
      for (int kg = 1; kg < 16; kg++) m = fmaxf(m, sc[kg][rg]);
      #pragma unroll
      for (int off = 1; off < 16; off <<= 1) m = fmaxf(m, __shfl_xor(m, off, 16));
      float ssum = 0.f;
      #pragma unroll
      for (int kg = 0; kg < 16; kg++){
        float p = __expf((sc[kg][rg] - m) * sc_);
        sc[kg][rg] = p; ssum += p;
      }
      #pragma unroll
      for (int off = 1; off < 16; off <<= 1) ssum += __shfl_xor(ssum, off, 16);
      inv_l[rg] = 1.f / ssum;
    }
    #pragma unroll
    for (int kg = 0; kg < 16; kg++)
      #pragma unroll
      for (int rg = 0; rg < 4; rg++)
        pw[(quad*4 + rg)*264 + kg*16 + l15] = f2b(sc[kg][rg]);
    ffrag oa[2];
    oa[0] = (ffrag){0.f,0.f,0.f,0.f};
    oa[1] = (ffrag){0.f,0.f,0.f,0.f};
    #pragma unroll
    for (int ks = 0; ks < 8; ks++){
      bfrag pa = *reinterpret_cast<const bfrag*>(&pw[l15*264 + ks*32 + quad*8]);
      #pragma unroll
      for (int n16 = 0; n16 < 2; n16++){
        bfrag bv = *reinterpret_cast<const bfrag*>(&Vt[(n16*16 + l15)*264 + ks*32 + quad*8]);
        oa[n16] = __builtin_amdgcn_mfma_f32_16x16x32_bf16(pa, bv, oa[n16], 0, 0, 0);
      }
    }
    #pragma unroll
    for (int n16 = 0; n16 < 2; n16++)
      #pragma unroll
      for (int rg = 0; rg < 4; rg++){
        int q = w*64 + qg*16 + quad*4 + rg;
        int col = hh*32 + n16*16 + l15;
        o[((size_t)(g<<8) + q)*128 + col] = oa[n16][rg] * inv_l[rg];
      }
  }
}

// ============================================================
// mean-pool + 2-layer head
// ============================================================
__global__ __launch_bounds__(256) void head_kernel(const float* __restrict__ h,
                                                   const float* __restrict__ W1, const float* __restrict__ b1,
                                                   const float* __restrict__ W2, const float* __restrict__ b2,
                                                   float* __restrict__ out){
  int g = blockIdx.x, tid = threadIdx.x;
  int c = tid & 127, half = tid >> 7;
  __shared__ float part[2][128];
  __shared__ float pool[128];
  __shared__ float hid[64];
  float s = 0.f;
  for (int n = half*128; n < half*128 + 128; n++)
    s += h[(size_t)((g<<8)+n)*128 + c];
  part[half][c] = s;
  __syncthreads();
  if (tid < 128) pool[tid] = (part[0][tid] + part[1][tid]) * (1.f/256.f);
  __syncthreads();
  if (tid < 64){
    float v = b1[tid];
    for (int k = 0; k < 128; k++) v += pool[k] * W1[k*64 + tid];
    hid[tid] = fmaxf(v, 0.f);
  }
  __syncthreads();
  if (tid == 0){
    float v = b2[0];
    for (int k = 0; k < 64; k++) v += hid[k] * W2[k];
    out[g] = v;
  }
}

// ============================================================
extern "C" void kernel_launch(void* const* d_in, const int* in_sizes, int n_in,
                              void* d_out, int out_size, void* d_ws, size_t ws_size,
                              hipStream_t stream){
  (void)in_sizes; (void)n_in; (void)out_size; (void)ws_size;
  const float* x      = (const float*)d_in[0];
  const float* eattr  = (const float*)d_in[1];
  const float* in_W   = (const float*)d_in[2];
  const float* in_b   = (const float*)d_in[3];
  const float* ep_W   = (const float*)d_in[4];
  const float* ep_b   = (const float*)d_in[5];
  const float* ge_W   = (const float*)d_in[6];
  const float* ge_b   = (const float*)d_in[7];
  const float* g1_W   = (const float*)d_in[8];
  const float* g1_b   = (const float*)d_in[9];
  const float* g2_W   = (const float*)d_in[10];
  const float* g2_b   = (const float*)d_in[11];
  const float* qkv_W  = (const float*)d_in[12];
  const float* qkv_b  = (const float*)d_in[13];
  const float* o_W    = (const float*)d_in[14];
  const float* o_b    = (const float*)d_in[15];
  const float* bn1g = (const float*)d_in[16]; const float* bn1b = (const float*)d_in[17];
  const float* bn1m = (const float*)d_in[18]; const float* bn1v = (const float*)d_in[19];
  const float* bn2g = (const float*)d_in[20]; const float* bn2b = (const float*)d_in[21];
  const float* bn2m = (const float*)d_in[22]; const float* bn2v = (const float*)d_in[23];
  const float* bn3g = (const float*)d_in[24]; const float* bn3b = (const float*)d_in[25];
  const float* bn3m = (const float*)d_in[26]; const float* bn3v = (const float*)d_in[27];
  const float* m1_W = (const float*)d_in[28]; const float* m1_b = (const float*)d_in[29];
  const float* m2_W = (const float*)d_in[30]; const float* m2_b = (const float*)d_in[31];
  const float* h1_W = (const float*)d_in[32]; const float* h1_b = (const float*)d_in[33];
  const float* h2_W = (const float*)d_in[34]; const float* h2_b = (const float*)d_in[35];
  const int*   ei   = (const int*)d_in[36];
  float* out = (float*)d_out;
  float* ws  = (float*)d_ws;
  int*   wsi = (int*)d_ws;

  // ---- workspace layout (fp32-element offsets) ----
  // phase-1 (dead after rwse_mf): A [0, 8.39M), Mbf [8.39M, 12.58M)
  const size_t oA    = 0;            // 8,388,608
  const size_t oMbf  = 8388608;      // 4,194,304 slots (8.4M ushort)
  // layer-time overlays of [0, 12.58M): Xin (2.1M), then QKV (12.58M) / T2 (8.39M)
  const size_t oXin  = 0;
  const size_t oQKV  = 0;
  const size_t oT2   = 0;            // t2 reuses qkv region (qkv dead after attn)
  // packed edges (alive pack -> end):
  const size_t oPk   = 12582912;     // 12,582,912 (32768*32*12)
  // persistent:
  const size_t oDeg  = 25165824;     // 32,768
  const size_t oPe   = 25198592;     // 655,360
  const size_t oH    = 25853952;     // 4,194,304
  const size_t oB1   = 30048256;     // 4,194,304  (ag = t1 = ob)
  const size_t oHO   = 34242560;     // 4,194,304  (h1 = out)
  const size_t oWp   = 38436864;     // 4,224
  const size_t oBp   = 38441088;     // 384
  const size_t oEpos = 38441472;     // 262,144 int
  const size_t oEcnt = 38703616;     // 32,768 int
  const size_t oWT   = 38736384;     // 499,712 ushort
  ushort* wt  = (ushort*)(ws + oWT);
  ushort* mbf = (ushort*)(ws + oMbf);

  // ---- build + RWSE (fused dense MFMA) ----
  hipMemsetAsync(ws + oA, 0, 8388608*sizeof(float), stream);
  hipMemsetAsync(wsi + oEcnt, 0, 32768*sizeof(int), stream);
  build_edges<<<NEDGE/256, 256, 0, stream>>>(ei, ws+oA, wsi+oEpos, wsi+oEcnt);
  pack_edges<<<NEDGE/256, 256, 0, stream>>>(ei, eattr, wsi+oEpos, ws+oPk);
  rwse_deg<<<GN, 256, 0, stream>>>(ws+oA, ws+oDeg);
  prep_m<<<GN, 256, 0, stream>>>(ws+oA, ws+oDeg, mbf);
  rwse_mf<<<GN*4, 256, 0, stream>>>(mbf, ws+oPe);

  // ---- weight prep ----
  prep_wt<<<dim3(192, 19), 256, 0, stream>>>(in_W, g1_W, g2_W, qkv_W, o_W, m1_W, m2_W, wt);

  // ---- input proj ----
  concat_kernel<<<NN*64/256, 256, 0, stream>>>(x, ws+oPe, ws+oXin);
  gemm_mf<64,false,false,false,false,false><<<512, 256, 0, stream>>>(
      ws+oXin, nullptr, wt + 0, in_b, nullptr, nullptr, nullptr, nullptr, nullptr, nullptr,
      ws+oH, 128, 1);

  wp_all<<<3, 256, 0, stream>>>(ep_W, ep_b, ge_W, ge_b, ws+oWp, ws+oBp);

  // ---- layers ----
  for (int i = 0; i < 3; i++){
    // ag -> B1
    gine_aggr2<<<NN/2, 256, 0, stream>>>(ws+oH, ws+oPk, wsi+oEcnt,
                                         ws+oWp + (size_t)i*1408, ws+oBp + (size_t)i*128, ws+oB1);
    // t1 = relu((h+ag)@g1+b1) -> B1 (row-partitioned in-place)
    gemm_mf<128,true,false,true,false,false><<<512, 256, 0, stream>>>(
        ws+oH, ws+oB1, wt + 8192 + (size_t)i*16384, g1_b + (size_t)i*128,
        nullptr, nullptr, nullptr, nullptr, nullptr, nullptr, ws+oB1, 128, 1);
    // h1 = BN1(t1@g2+b2 + h) -> HO
    gemm_mf<128,false,true,false,true,false><<<512, 256, 0, stream>>>(
        ws+oB1, nullptr, wt + 57344 + (size_t)i*16384, g2_b + (size_t)i*128,
        ws+oH, nullptr, bn1g+(size_t)i*128, bn1b+(size_t)i*128, bn1m+(size_t)i*128, bn1v+(size_t)i*128,
        ws+oHO, 128, 1);
    // qkv
    gemm_mf<128,false,false,false,false,false><<<1536, 256, 0, stream>>>(
        ws+oH, nullptr, wt + 106496 + (size_t)i*49152, qkv_b + (size_t)i*384,
        nullptr, nullptr, nullptr, nullptr, nullptr, nullptr, ws+oQKV, 384, 3);
    // ob -> B1 (t1 dead)
    attn_mf<<<GN*4, 256, 0, stream>>>(ws+oQKV, ws+oB1);
    // out = BN2(ob@oW+ob_b + h) + h1 -> HO (reads R2p=h1 elementwise before write)
    gemm_mf<128,false,true,false,true,true><<<512, 256, 0, stream>>>(
        ws+oB1, nullptr, wt + 253952 + (size_t)i*16384, o_b + (size_t)i*128,
        ws+oH, ws+oHO, bn2g+(size_t)i*128, bn2b+(size_t)i*128, bn2m+(size_t)i*128, bn2v+(size_t)i*128,
        ws+oHO, 128, 1);
    // t2 = relu(out@m1+b) -> QKV region (qkv dead)
    gemm_mf<128,true,false,false,false,false><<<1024, 256, 0, stream>>>(
        ws+oHO, nullptr, wt + 303104 + (size_t)i*32768, m1_b + (size_t)i*256,
        nullptr, nullptr, nullptr, nullptr, nullptr, nullptr, ws+oT2, 256, 2);
    // h = BN3(t2@m2+b + out)
    gemm_mf<256,false,true,false,true,false><<<512, 256, 0, stream>>>(
        ws+oT2, nullptr, wt + 401408 + (size_t)i*32768, m2_b + (size_t)i*128,
        ws+oHO, nullptr, bn3g+(size_t)i*128, bn3b+(size_t)i*128, bn3m+(size_t)i*128, bn3v+(size_t)i*128,
        ws+oH, 128, 1);
  }

  head_kernel<<<GN, 256, 0, stream>>>(ws+oH, h1_W, h1_b, h2_W, h2_b, out);
}

// Round 6
// 737.741 us; speedup vs baseline: 4.8814x; 1.1187x over previous
//
#include <hip/hip_runtime.h>

#define GN   128      // graphs
#define GP   256      // nodes per graph
#define NN   32768    // total nodes
#define NEDGE 262144  // total edges
#define WALKN 20

typedef __attribute__((ext_vector_type(8))) short bfrag;   // 8 bf16 (4 VGPRs)
typedef __attribute__((ext_vector_type(4))) float ffrag;   // 4 fp32 acc

__device__ __forceinline__ ushort f2b(float f){
  unsigned u = __float_as_uint(f);
  u += 0x7fffu + ((u >> 16) & 1u);      // RNE
  return (ushort)(u >> 16);
}
__device__ __forceinline__ float b2f(ushort u){
  return __uint_as_float(((unsigned)u) << 16);
}
// add two bf16 pairs (packed in uint) in fp32, re-round
__device__ __forceinline__ unsigned addpair(unsigned a, unsigned b){
  float alo = __uint_as_float(a << 16), ahi = __uint_as_float(a & 0xffff0000u);
  float blo = __uint_as_float(b << 16), bhi = __uint_as_float(b & 0xffff0000u);
  return ((unsigned)f2b(ahi + bhi) << 16) | (unsigned)f2b(alo + blo);
}

// ============================================================
// build A (dense counts) + per-edge dst slot
// ============================================================
__global__ __launch_bounds__(256) void build_edges(const int* __restrict__ ei, float* __restrict__ A,
                                                   int* __restrict__ epos, int* __restrict__ Ecnt){
  int e = blockIdx.x*256 + threadIdx.x;
  int s = ei[e], d = ei[NEDGE + e];
  int g = s >> 8;
  atomicAdd(&A[((size_t)g<<16) + ((size_t)(s&255)<<8) + (size_t)(d&255)], 1.0f);
  epos[e] = atomicAdd(&Ecnt[d], 1);
}

// pack {src, ea[0..10]} grouped by dst (48B records, 32 slots/node)
__global__ __launch_bounds__(256) void pack_edges(const int* __restrict__ ei, const float* __restrict__ ea,
                                                  const int* __restrict__ epos, float* __restrict__ pk){
  int e = blockIdx.x*256 + threadIdx.x;
  int d = ei[NEDGE + e];
  int pos = epos[e];
  if (pos >= 32) return;
  float* dst = pk + ((size_t)d*32 + pos)*12;
  dst[0] = __int_as_float(ei[e]);
  const float* s = ea + (size_t)e*11;
  #pragma unroll
  for (int t = 0; t < 11; t++) dst[1+t] = s[t];
}

// add self loops + out-degree
__global__ __launch_bounds__(256) void rwse_deg(float* __restrict__ A, float* __restrict__ deg){
  int g = blockIdx.x, r = threadIdx.x;
  float* row = A + ((size_t)g<<16) + ((size_t)r<<8);
  row[r] += 1.0f;
  float s = 0.f;
  for (int c = 0; c < 256; c += 4){
    float4 v = *(const float4*)&row[c];
    s += v.x + v.y + v.z + v.w;
  }
  deg[(g<<8)+r] = fmaxf(s, 1.0f);
}

// dense bf16 M[c][r] = A[r][c]/deg[r]
__global__ __launch_bounds__(256) void prep_m(const float* __restrict__ A, const float* __restrict__ deg,
                                              ushort* __restrict__ Mbf){
  __shared__ float As[64][65];
  __shared__ float Bs[64][65];
  __shared__ float invd[256];
  int g = blockIdx.x;
  const float* Ag = A + ((size_t)g<<16);
  int tid = threadIdx.x, tx = tid & 63, ty = tid >> 6;
  invd[tid] = 1.f / deg[(g<<8)+tid];
  ushort* Mg = Mbf + ((size_t)g<<16);
  const int pr[10] = {0,0,0,0,1,1,1,2,2,3};
  const int pc[10] = {0,1,2,3,1,2,3,2,3,3};
  for (int t = 0; t < 10; t++){
    int R0 = pr[t]*64, C0 = pc[t]*64;
    __syncthreads();
    #pragma unroll
    for (int i = 0; i < 16; i++){
      As[ty + i*4][tx] = Ag[(size_t)(R0 + ty + i*4)*256 + C0 + tx];
      Bs[ty + i*4][tx] = Ag[(size_t)(C0 + ty + i*4)*256 + R0 + tx];
    }
    __syncthreads();
    #pragma unroll
    for (int i = 0; i < 16; i++){
      int cl = ty + i*4;
      Mg[(size_t)(C0+cl)*256 + R0+tx] = f2b(As[tx][cl] * invd[R0+tx]);
      if (R0 != C0)
        Mg[(size_t)(R0+cl)*256 + C0+tx] = f2b(Bs[tx][cl] * invd[C0+tx]);
    }
  }
}

// ============================================================
// ALL 20 walk steps in one kernel (P^T slice LDS-resident)
// ============================================================
__global__ __launch_bounds__(256, 2) void rwse_mf(const ushort* __restrict__ Mbf,
                                                  float* __restrict__ pe){
  __shared__ __align__(16) ushort Pt[64*264];
  int bid = blockIdx.x;
  int g  = (bid & 7)*16 + (bid >> 5);
  int cb = ((bid >> 3) & 3) << 6;
  int tid = threadIdx.x, lane = tid & 63, w = tid >> 6;
  int l15 = lane & 15, quad = lane >> 4;
  const ushort* Mg = Mbf + ((size_t)g << 16);
  uint4 z4; z4.x = z4.y = z4.z = z4.w = 0u;
  for (int i = tid; i < 2112; i += 256) reinterpret_cast<uint4*>(Pt)[i] = z4;
  __syncthreads();
  if (tid < 64) Pt[tid*264 + cb + tid] = 0x3F80;
  __syncthreads();

  for (int s = 0; s < WALKN; s++){
    ffrag acc[4][4];
    #pragma unroll
    for (int mi = 0; mi < 4; mi++)
      #pragma unroll
      for (int n = 0; n < 4; n++) acc[mi][n] = (ffrag){0.f,0.f,0.f,0.f};
    for (int k0 = 0; k0 < 256; k0 += 32){
      bfrag a[4], b[4];
      #pragma unroll
      for (int mi = 0; mi < 4; mi++)
        a[mi] = *reinterpret_cast<const bfrag*>(&Mg[(size_t)(w*64 + mi*16 + l15)*256 + k0 + quad*8]);
      #pragma unroll
      for (int n = 0; n < 4; n++)
        b[n] = *reinterpret_cast<const bfrag*>(&Pt[(n*16 + l15)*264 + k0 + quad*8]);
      #pragma unroll
      for (int mi = 0; mi < 4; mi++)
        #pragma unroll
        for (int n = 0; n < 4; n++)
          acc[mi][n] = __builtin_amdgcn_mfma_f32_16x16x32_bf16(a[mi], b[n], acc[mi][n], 0, 0, 0);
    }
    __syncthreads();
    #pragma unroll
    for (int mi = 0; mi < 4; mi++){
      int rbase = w*64 + mi*16 + quad*4;
      #pragma unroll
      for (int n = 0; n < 4; n++){
        int cl = n*16 + l15;
        int dd = cb + cl - rbase;
        if (dd >= 0 && dd < 4){
          float dv = (dd==0)?acc[mi][n][0]:(dd==1)?acc[mi][n][1]:(dd==2)?acc[mi][n][2]:acc[mi][n][3];
          pe[(size_t)((g<<8) + cb + cl)*WALKN + s] = dv;
        }
        ushort4 pkk;
        pkk.x = f2b(acc[mi][n][0]); pkk.y = f2b(acc[mi][n][1]);
        pkk.z = f2b(acc[mi][n][2]); pkk.w = f2b(acc[mi][n][3]);
        *reinterpret_cast<ushort4*>(&Pt[cl*264 + rbase]) = pkk;
      }
    }
    __syncthreads();
  }
}

// ============================================================
// concat [x | pe | 0pad] -> xinb [N,64] bf16
// ============================================================
__global__ __launch_bounds__(256) void concat_kernel(const float* __restrict__ x, const float* __restrict__ pe,
                                                     ushort* __restrict__ xinb){
  int idx = blockIdx.x*256 + threadIdx.x;
  int row = idx >> 6, c = idx & 63;
  float v = 0.f;
  if (c < 30) v = x[(size_t)row*30 + c];
  else if (c < 50) v = pe[(size_t)row*20 + (c-30)];
  xinb[idx] = f2b(v);
}

// ============================================================
// prep: all weights -> bf16 transposed [N][Kp] (B-operand layout)
// ============================================================
__global__ __launch_bounds__(256) void prep_wt(const float* __restrict__ in_W, const float* __restrict__ g1_W,
                                               const float* __restrict__ g2_W, const float* __restrict__ qkv_W,
                                               const float* __restrict__ o_W, const float* __restrict__ m1_W,
                                               const float* __restrict__ m2_W, ushort* __restrict__ wt){
  int rgn = blockIdx.y;
  const float* src; int K, N, Kp; size_t dst;
  if (rgn == 0){ src = in_W; K=50; N=128; Kp=64; dst = 0; }
  else if (rgn <= 3){ int i=rgn-1;  src = g1_W + (size_t)i*16384; K=128; N=128; Kp=128; dst = 8192   + (size_t)i*16384; }
  else if (rgn <= 6){ int i=rgn-4;  src = g2_W + (size_t)i*16384; K=128; N=128; Kp=128; dst = 57344  + (size_t)i*16384; }
  else if (rgn <= 9){ int i=rgn-7;  src = qkv_W+ (size_t)i*49152; K=128; N=384; Kp=128; dst = 106496 + (size_t)i*49152; }
  else if (rgn <= 12){ int i=rgn-10; src = o_W  + (size_t)i*16384; K=128; N=128; Kp=128; dst = 253952 + (size_t)i*16384; }
  else if (rgn <= 15){ int i=rgn-13; src = m1_W + (size_t)i*32768; K=128; N=256; Kp=128; dst = 303104 + (size_t)i*32768; }
  else               { int i=rgn-16; src = m2_W + (size_t)i*32768; K=256; N=128; Kp=256; dst = 401408 + (size_t)i*32768; }
  int sz = N * Kp;
  int idx = blockIdx.x*256 + threadIdx.x;
  if (idx >= sz) return;
  int n = idx / Kp, kp = idx - n*Kp;
  float v = (kp < K) ? src[(size_t)kp*N + n] : 0.f;
  wt[dst + idx] = f2b(v);
}

// ============================================================
// plain bf16 GEMM (bias only): Y[bf16] = X[bf16] @ W + b
// ============================================================
template<int CINP>
__global__ __launch_bounds__(256, 2) void gemm_b(
    const ushort* __restrict__ X1, const ushort* __restrict__ WT,
    const float* __restrict__ bias, ushort* __restrict__ Y, int ldY, int colTiles)
{
  constexpr int XS = CINP + 8;
  __shared__ ushort XA[64 * XS];
  __shared__ ushort WS[128 * XS];
  int bt = blockIdx.x;
  int row0 = (bt / colTiles) * 64;
  int c0   = (bt % colTiles) * 128;
  int tid = threadIdx.x;
  int lane = tid & 63, wave = tid >> 6;
  int l15 = lane & 15, quad = lane >> 4;
  int wr = wave >> 1, wc = wave & 1;
  constexpr int C8 = CINP/8;

  #pragma unroll
  for (int it = 0; it < CINP/32; it++){
    int idx = tid + it*256;
    int r = idx / C8, c8 = (idx % C8)*8;
    *reinterpret_cast<uint4*>(&XA[r*XS + c8]) =
        *reinterpret_cast<const uint4*>(&X1[(size_t)(row0+r)*CINP + c8]);
  }
  #pragma unroll
  for (int it = 0; it < CINP/16; it++){
    int idx = tid + it*256;
    int n = idx / C8, c8 = (idx % C8)*8;
    *reinterpret_cast<uint4*>(&WS[n*XS + c8]) =
        *reinterpret_cast<const uint4*>(&WT[(size_t)(c0+n)*CINP + c8]);
  }
  __syncthreads();
  ffrag acc[2][4];
  #pragma unroll
  for (int m = 0; m < 2; m++)
    #pragma unroll
    for (int n = 0; n < 4; n++) acc[m][n] = (ffrag){0.f,0.f,0.f,0.f};
  #pragma unroll
  for (int ks = 0; ks < CINP/32; ks++){
    bfrag a[2], b[4];
    #pragma unroll
    for (int m = 0; m < 2; m++)
      a[m] = *reinterpret_cast<const bfrag*>(&XA[(32*wr + 16*m + l15)*XS + ks*32 + quad*8]);
    #pragma unroll
    for (int n = 0; n < 4; n++)
      b[n] = *reinterpret_cast<const bfrag*>(&WS[(64*wc + 16*n + l15)*XS + ks*32 + quad*8]);
    #pragma unroll
    for (int m = 0; m < 2; m++)
      #pragma unroll
      for (int n = 0; n < 4; n++)
        acc[m][n] = __builtin_amdgcn_mfma_f32_16x16x32_bf16(a[m], b[n], acc[m][n], 0, 0, 0);
  }
  #pragma unroll
  for (int m = 0; m < 2; m++)
    #pragma unroll
    for (int n = 0; n < 4; n++){
      int col = c0 + 64*wc + 16*n + l15;
      float bs = bias[col];
      #pragma unroll
      for (int rg = 0; rg < 4; rg++){
        int r = row0 + 32*wr + 16*m + quad*4 + rg;
        Y[(size_t)r*ldY + col] = f2b(acc[m][n][rg] + bs);
      }
    }
}

// ============================================================
// fused GINE MLP: h1 = BN1( relu((h+ag)@g1+b1) @ g2 + b2 + h )
// ============================================================
__global__ __launch_bounds__(256, 2) void gine_mlp(
    const ushort* __restrict__ hb, const ushort* __restrict__ agb,
    const ushort* __restrict__ w1, const float* __restrict__ b1v,
    const ushort* __restrict__ w2, const float* __restrict__ b2v,
    const float* __restrict__ bng, const float* __restrict__ bnb,
    const float* __restrict__ bnm, const float* __restrict__ bnv,
    ushort* __restrict__ h1b)
{
  __shared__ ushort XA[64*136];
  __shared__ ushort WS[128*136];
  __shared__ ushort T1[64*136];
  int row0 = blockIdx.x * 64;
  int tid = threadIdx.x, lane = tid & 63, wave = tid >> 6;
  int l15 = lane & 15, quad = lane >> 4;
  int wr = wave >> 1, wc = wave & 1;

  #pragma unroll
  for (int it = 0; it < 4; it++){
    int idx = tid + it*256;
    int r = idx >> 4, c8 = (idx & 15)*8;
    uint4 av = *reinterpret_cast<const uint4*>(&hb[(size_t)(row0+r)*128 + c8]);
    uint4 bv = *reinterpret_cast<const uint4*>(&agb[(size_t)(row0+r)*128 + c8]);
    uint4 o; o.x=addpair(av.x,bv.x); o.y=addpair(av.y,bv.y); o.z=addpair(av.z,bv.z); o.w=addpair(av.w,bv.w);
    *reinterpret_cast<uint4*>(&XA[r*136 + c8]) = o;
  }
  #pragma unroll
  for (int it = 0; it < 8; it++){
    int idx = tid + it*256;
    int n = idx >> 4, c8 = (idx & 15)*8;
    *reinterpret_cast<uint4*>(&WS[n*136 + c8]) =
        *reinterpret_cast<const uint4*>(&w1[(size_t)n*128 + c8]);
  }
  __syncthreads();
  ffrag acc[2][4];
  #pragma unroll
  for (int m = 0; m < 2; m++)
    #pragma unroll
    for (int n = 0; n < 4; n++) acc[m][n] = (ffrag){0.f,0.f,0.f,0.f};
  #pragma unroll
  for (int ks = 0; ks < 4; ks++){
    bfrag a[2], b[4];
    #pragma unroll
    for (int m = 0; m < 2; m++)
      a[m] = *reinterpret_cast<const bfrag*>(&XA[(32*wr + 16*m + l15)*136 + ks*32 + quad*8]);
    #pragma unroll
    for (int n = 0; n < 4; n++)
      b[n] = *reinterpret_cast<const bfrag*>(&WS[(64*wc + 16*n + l15)*136 + ks*32 + quad*8]);
    #pragma unroll
    for (int m = 0; m < 2; m++)
      #pragma unroll
      for (int n = 0; n < 4; n++)
        acc[m][n] = __builtin_amdgcn_mfma_f32_16x16x32_bf16(a[m], b[n], acc[m][n], 0, 0, 0);
  }
  __syncthreads();          // all WS/XA reads done
  // t1 -> LDS (relu), reload WS = w2
  #pragma unroll
  for (int m = 0; m < 2; m++)
    #pragma unroll
    for (int n = 0; n < 4; n++){
      int col = 64*wc + 16*n + l15;
      float bs = b1v[col];
      #pragma unroll
      for (int rg = 0; rg < 4; rg++){
        int rl = 32*wr + 16*m + quad*4 + rg;
        T1[rl*136 + col] = f2b(fmaxf(acc[m][n][rg] + bs, 0.f));
      }
    }
  #pragma unroll
  for (int it = 0; it < 8; it++){
    int idx = tid + it*256;
    int n = idx >> 4, c8 = (idx & 15)*8;
    *reinterpret_cast<uint4*>(&WS[n*136 + c8]) =
        *reinterpret_cast<const uint4*>(&w2[(size_t)n*128 + c8]);
  }
  __syncthreads();
  #pragma unroll
  for (int m = 0; m < 2; m++)
    #pragma unroll
    for (int n = 0; n < 4; n++) acc[m][n] = (ffrag){0.f,0.f,0.f,0.f};
  #pragma unroll
  for (int ks = 0; ks < 4; ks++){
    bfrag a[2], b[4];
    #pragma unroll
    for (int m = 0; m < 2; m++)
      a[m] = *reinterpret_cast<const bfrag*>(&T1[(32*wr + 16*m + l15)*136 + ks*32 + quad*8]);
    #pragma unroll
    for (int n = 0; n < 4; n++)
      b[n] = *reinterpret_cast<const bfrag*>(&WS[(64*wc + 16*n + l15)*136 + ks*32 + quad*8]);
    #pragma unroll
    for (int m = 0; m < 2; m++)
      #pragma unroll
      for (int n = 0; n < 4; n++)
        acc[m][n] = __builtin_amdgcn_mfma_f32_16x16x32_bf16(a[m], b[n], acc[m][n], 0, 0, 0);
  }
  #pragma unroll
  for (int m = 0; m < 2; m++)
    #pragma unroll
    for (int n = 0; n < 4; n++){
      int col = 64*wc + 16*n + l15;
      float bs = b2v[col];
      float sc = rsqrtf(bnv[col] + 1e-5f) * bng[col];
      float sh = bnb[col] - bnm[col]*sc;
      #pragma unroll
      for (int rg = 0; rg < 4; rg++){
        int r = row0 + 32*wr + 16*m + quad*4 + rg;
        float v = acc[m][n][rg] + bs + b2f(hb[(size_t)r*128 + col]);
        h1b[(size_t)r*128 + col] = f2b(v*sc + sh);
      }
    }
}

// ============================================================
// fused FF tail: out = BN2(ob@oW+b + h) + h1 ; t2 = relu(out@m1+b) ;
//                hnew = BN3(t2@m2+b + out)       (out,t2 LDS-resident)
// ============================================================
__global__ __launch_bounds__(256, 1) void ff_fused(
    const ushort* __restrict__ obb, const ushort* __restrict__ hb, const ushort* __restrict__ h1b,
    const ushort* __restrict__ wo, const float* __restrict__ ob_b,
    const float* __restrict__ bn2g, const float* __restrict__ bn2b,
    const float* __restrict__ bn2m, const float* __restrict__ bn2v,
    const ushort* __restrict__ wm1, const float* __restrict__ m1b,
    const ushort* __restrict__ wm2, const float* __restrict__ m2b,
    const float* __restrict__ bn3g, const float* __restrict__ bn3b,
    const float* __restrict__ bn3m, const float* __restrict__ bn3v,
    ushort* __restrict__ hout)
{
  __shared__ ushort XA[64*136];     // ob tile
  __shared__ ushort WS[256*136];    // weights (oW / m1 / m2 layouts)
  __shared__ ushort OUT[64*136];    // 'out' tile
  __shared__ ushort T2[64*264];     // t2 tile
  int row0 = blockIdx.x * 64;
  int tid = threadIdx.x, lane = tid & 63, wave = tid >> 6;
  int l15 = lane & 15, quad = lane >> 4;
  int wr = wave >> 1, wc = wave & 1;

  #pragma unroll
  for (int it = 0; it < 4; it++){
    int idx = tid + it*256;
    int r = idx >> 4, c8 = (idx & 15)*8;
    *reinterpret_cast<uint4*>(&XA[r*136 + c8]) =
        *reinterpret_cast<const uint4*>(&obb[(size_t)(row0+r)*128 + c8]);
  }
  #pragma unroll
  for (int it = 0; it < 8; it++){
    int idx = tid + it*256;
    int n = idx >> 4, c8 = (idx & 15)*8;
    *reinterpret_cast<uint4*>(&WS[n*136 + c8]) =
        *reinterpret_cast<const uint4*>(&wo[(size_t)n*128 + c8]);
  }
  __syncthreads();
  // phase 1: o-proj
  ffrag acc[2][4];
  #pragma unroll
  for (int m = 0; m < 2; m++)
    #pragma unroll
    for (int n = 0; n < 4; n++) acc[m][n] = (ffrag){0.f,0.f,0.f,0.f};
  #pragma unroll
  for (int ks = 0; ks < 4; ks++){
    bfrag a[2], b[4];
    #pragma unroll
    for (int m = 0; m < 2; m++)
      a[m] = *reinterpret_cast<const bfrag*>(&XA[(32*wr + 16*m + l15)*136 + ks*32 + quad*8]);
    #pragma unroll
    for (int n = 0; n < 4; n++)
      b[n] = *reinterpret_cast<const bfrag*>(&WS[(64*wc + 16*n + l15)*136 + ks*32 + quad*8]);
    #pragma unroll
    for (int m = 0; m < 2; m++)
      #pragma unroll
      for (int n = 0; n < 4; n++)
        acc[m][n] = __builtin_amdgcn_mfma_f32_16x16x32_bf16(a[m], b[n], acc[m][n], 0, 0, 0);
  }
  __syncthreads();
  // out -> OUT (BN2 + h residual + h1 residual), reload WS = m1
  #pragma unroll
  for (int m = 0; m < 2; m++)
    #pragma unroll
    for (int n = 0; n < 4; n++){
      int col = 64*wc + 16*n + l15;
      float bs = ob_b[col];
      float sc = rsqrtf(bn2v[col] + 1e-5f) * bn2g[col];
      float sh = bn2b[col] - bn2m[col]*sc;
      #pragma unroll
      for (int rg = 0; rg < 4; rg++){
        int rl = 32*wr + 16*m + quad*4 + rg;
        int r = row0 + rl;
        float v = acc[m][n][rg] + bs + b2f(hb[(size_t)r*128 + col]);
        v = v*sc + sh + b2f(h1b[(size_t)r*128 + col]);
        OUT[rl*136 + col] = f2b(v);
      }
    }
  #pragma unroll
  for (int it = 0; it < 16; it++){
    int idx = tid + it*256;
    int n = idx >> 4, c8 = (idx & 15)*8;
    *reinterpret_cast<uint4*>(&WS[n*136 + c8]) =
        *reinterpret_cast<const uint4*>(&wm1[(size_t)n*128 + c8]);
  }
  __syncthreads();
  // phase 2: m1 (64x256 out), wave = 32 rows x 128 cols
  ffrag acc2[2][8];
  #pragma unroll
  for (int m = 0; m < 2; m++)
    #pragma unroll
    for (int n = 0; n < 8; n++) acc2[m][n] = (ffrag){0.f,0.f,0.f,0.f};
  #pragma unroll
  for (int ks = 0; ks < 4; ks++){
    bfrag a[2], b[8];
    #pragma unroll
    for (int m = 0; m < 2; m++)
      a[m] = *reinterpret_cast<const bfrag*>(&OUT[(32*wr + 16*m + l15)*136 + ks*32 + quad*8]);
    #pragma unroll
    for (int n = 0; n < 8; n++)
      b[n] = *reinterpret_cast<const bfrag*>(&WS[(128*wc + 16*n + l15)*136 + ks*32 + quad*8]);
    #pragma unroll
    for (int m = 0; m < 2; m++)
      #pragma unroll
      for (int n = 0; n < 8; n++)
        acc2[m][n] = __builtin_amdgcn_mfma_f32_16x16x32_bf16(a[m], b[n], acc2[m][n], 0, 0, 0);
  }
  __syncthreads();
  // t2 -> T2 (relu), reload WS = m2 [128n][264k-padded]
  #pragma unroll
  for (int m = 0; m < 2; m++)
    #pragma unroll
    for (int n = 0; n < 8; n++){
      int col = 128*wc + 16*n + l15;
      float bs = m1b[col];
      #pragma unroll
      for (int rg = 0; rg < 4; rg++){
        int rl = 32*wr + 16*m + quad*4 + rg;
        T2[rl*264 + col] = f2b(fmaxf(acc2[m][n][rg] + bs, 0.f));
      }
    }
  #pragma unroll
  for (int it = 0; it < 16; it++){
    int idx = tid + it*256;
    int n = idx >> 5, c8 = (idx & 31)*8;
    *reinterpret_cast<uint4*>(&WS[n*264 + c8]) =
        *reinterpret_cast<const uint4*>(&wm2[(size_t)n*256 + c8]);
  }
  __syncthreads();
  // phase 3: m2 (K=256)
  #pragma unroll
  for (int m = 0; m < 2; m++)
    #pragma unroll
    for (int n = 0; n < 4; n++) acc[m][n] = (ffrag){0.f,0.f,0.f,0.f};
  #pragma unroll
  for (int ks = 0; ks < 8; ks++){
    bfrag a[2], b[4];
    #pragma unroll
    for (int m = 0; m < 2; m++)
      a[m] = *reinterpret_cast<const bfrag*>(&T2[(32*wr + 16*m + l15)*264 + ks*32 + quad*8]);
    #pragma unroll
    for (int n = 0; n < 4; n++)
      b[n] = *reinterpret_cast<const bfrag*>(&WS[(64*wc + 16*n + l15)*264 + ks*32 + quad*8]);
    #pragma unroll
    for (int m = 0; m < 2; m++)
      #pragma unroll
      for (int n = 0; n < 4; n++)
        acc[m][n] = __builtin_amdgcn_mfma_f32_16x16x32_bf16(a[m], b[n], acc[m][n], 0, 0, 0);
  }
  #pragma unroll
  for (int m = 0; m < 2; m++)
    #pragma unroll
    for (int n = 0; n < 4; n++){
      int col = 64*wc + 16*n + l15;
      float bs = m2b[col];
      float sc = rsqrtf(bn3v[col] + 1e-5f) * bn3g[col];
      float sh = bn3b[col] - bn3m[col]*sc;
      #pragma unroll
      for (int rg = 0; rg < 4; rg++){
        int rl = 32*wr + 16*m + quad*4 + rg;
        float v = acc[m][n][rg] + bs + b2f(OUT[rl*136 + col]);
        hout[(size_t)(row0+rl)*128 + col] = f2b(v*sc + sh);
      }
    }
}

// ============================================================
// per-layer collapsed edge weights
// ============================================================
__global__ __launch_bounds__(256) void wp_all(const float* __restrict__ epW, const float* __restrict__ epb,
                                              const float* __restrict__ geW, const float* __restrict__ geb,
                                              float* __restrict__ Wp, float* __restrict__ bp){
  int i = blockIdx.x;
  const float* gw = geW + (size_t)i*16384;
  float* wp = Wp + (size_t)i*1408;
  int tid = threadIdx.x;
  for (int idx = tid; idx < 1408; idx += 256){
    int t = idx >> 7, c = idx & 127;
    float s = 0.f;
    for (int k = 0; k < 128; k++) s += epW[t*128+k] * gw[(size_t)k*128 + c];
    wp[idx] = s;
  }
  if (tid < 128){
    float s = geb[(size_t)i*128 + tid];
    for (int k = 0; k < 128; k++) s += epb[k] * gw[(size_t)k*128 + tid];
    bp[(size_t)i*128 + tid] = s;
  }
}

// ============================================================
// GINE aggregation, bf16 h in, bf16 aggr out
// ============================================================
__global__ __launch_bounds__(256) void gine_aggr2(const ushort* __restrict__ hb, const float* __restrict__ pk,
                                                  const int* __restrict__ Ecnt,
                                                  const float* __restrict__ Wp, const float* __restrict__ bp,
                                                  ushort* __restrict__ agb){
  int n = blockIdx.x*2 + (threadIdx.x >> 7);
  int ch = threadIdx.x & 127;
  int cnt = Ecnt[n]; if (cnt > 32) cnt = 32;
  float wreg[11];
  #pragma unroll
  for (int t = 0; t < 11; t++) wreg[t] = Wp[t*128 + ch];
  float bpc = bp[ch];
  const float* pkn = pk + (size_t)n*384;
  float acc = 0.f;
  int j = 0;
  for (; j + 4 <= cnt; j += 4){
    const float* p0 = pkn + (size_t)(j+0)*12;
    const float* p1 = pkn + (size_t)(j+1)*12;
    const float* p2 = pkn + (size_t)(j+2)*12;
    const float* p3 = pkn + (size_t)(j+3)*12;
    int s0 = __float_as_int(p0[0]), s1 = __float_as_int(p1[0]);
    int s2 = __float_as_int(p2[0]), s3 = __float_as_int(p3[0]);
    float h0 = b2f(hb[(size_t)s0*128 + ch]);
    float h1 = b2f(hb[(size_t)s1*128 + ch]);
    float h2 = b2f(hb[(size_t)s2*128 + ch]);
    float h3 = b2f(hb[(size_t)s3*128 + ch]);
    float e0 = bpc, e1 = bpc, e2 = bpc, e3 = bpc;
    #pragma unroll
    for (int t = 0; t < 11; t++){
      e0 += p0[1+t]*wreg[t]; e1 += p1[1+t]*wreg[t];
      e2 += p2[1+t]*wreg[t]; e3 += p3[1+t]*wreg[t];
    }
    acc += fmaxf(h0+e0, 0.f) + fmaxf(h1+e1, 0.f) + fmaxf(h2+e2, 0.f) + fmaxf(h3+e3, 0.f);
  }
  for (; j < cnt; j++){
    const float* p0 = pkn + (size_t)j*12;
    int s0 = __float_as_int(p0[0]);
    float h0 = b2f(hb[(size_t)s0*128 + ch]);
    float e0 = bpc;
    #pragma unroll
    for (int t = 0; t < 11; t++) e0 += p0[1+t]*wreg[t];
    acc += fmaxf(h0+e0, 0.f);
  }
  agb[(size_t)n*128 + ch] = f2b(acc);
}

// ============================================================
// MFMA attention, bf16 qkv in, bf16 out
// ============================================================
__global__ __launch_bounds__(256, 2) void attn_mf(const ushort* __restrict__ qkvb, ushort* __restrict__ obb){
  __shared__ ushort Ks[256 * 40];
  __shared__ ushort Vt[32 * 264];
  __shared__ ushort PA[4 * 16 * 264];
  int g = blockIdx.x >> 2, hh = blockIdx.x & 3;
  int tid = threadIdx.x, lane = tid & 63, w = tid >> 6;
  int l15 = lane & 15, quad = lane >> 4;
  const ushort* base = qkvb + (size_t)(g<<8)*384;

  #pragma unroll
  for (int it = 0; it < 4; it++){
    int idx = tid + it*256;              // 1024 x (8 ushorts) over 256x32
    int key = idx >> 2, d8 = (idx & 3)*8;
    uint4 kv = *reinterpret_cast<const uint4*>(&base[(size_t)key*384 + 128 + hh*32 + d8]);
    *reinterpret_cast<uint4*>(&Ks[key*40 + d8]) = kv;
    uint4 vv = *reinterpret_cast<const uint4*>(&base[(size_t)key*384 + 256 + hh*32 + d8]);
    const ushort* vp = reinterpret_cast<const ushort*>(&vv);
    #pragma unroll
    for (int t = 0; t < 8; t++) Vt[(d8+t)*264 + key] = vp[t];
  }
  bfrag qf[4];
  #pragma unroll
  for (int qg = 0; qg < 4; qg++){
    int q = w*64 + qg*16 + l15;
    qf[qg] = *reinterpret_cast<const bfrag*>(&base[(size_t)q*384 + hh*32 + quad*8]);
  }
  __syncthreads();

  ushort* pw = &PA[w * 16 * 264];
  const float sc_ = 0.17677669529663687f;
  for (int qg = 0; qg < 4; qg++){
    ffrag sc[16];
    #pragma unroll
    for (int kg = 0; kg < 16; kg++){
      bfrag bk = *reinterpret_cast<const bfrag*>(&Ks[(kg*16 + l15)*40 + quad*8]);
      ffrag z = (ffrag){0.f,0.f,0.f,0.f};
      sc[kg] = __builtin_amdgcn_mfma_f32_16x16x32_bf16(qf[qg], bk, z, 0, 0, 0);
    }
    float inv_l[4];
    #pragma unroll
    for (int rg = 0; rg < 4; rg++){
      float m = sc[0][rg];
      #pragma unroll
      for (int kg = 1; kg < 16; kg++) m = fmaxf(m, sc[kg][rg]);
      #pragma unroll
      for (int off = 1; off < 16; off <<= 1) m = fmaxf(m, __shfl_xor(m, off, 16));
      float ssum = 0.f;
      #pragma unroll
      for (int kg = 0; kg < 16; kg++){
        float p = __expf((sc[kg][rg] - m) * sc_);
        sc[kg][rg] = p; ssum += p;
      }
      #pragma unroll
      for (int off = 1; off < 16; off <<= 1) ssum += __shfl_xor(ssum, off, 16);
      inv_l[rg] = 1.f / ssum;
    }
    #pragma unroll
    for (int kg = 0; kg < 16; kg++)
      #pragma unroll
      for (int rg = 0; rg < 4; rg++)
        pw[(quad*4 + rg)*264 + kg*16 + l15] = f2b(sc[kg][rg]);
    ffrag oa[2];
    oa[0] = (ffrag){0.f,0.f,0.f,0.f};
    oa[1] = (ffrag){0.f,0.f,0.f,0.f};
    #pragma unroll
    for (int ks = 0; ks < 8; ks++){
      bfrag pa = *reinterpret_cast<const bfrag*>(&pw[l15*264 + ks*32 + quad*8]);
      #pragma unroll
      for (int n16 = 0; n16 < 2; n16++){
        bfrag bv = *reinterpret_cast<const bfrag*>(&Vt[(n16*16 + l15)*264 + ks*32 + quad*8]);
        oa[n16] = __builtin_amdgcn_mfma_f32_16x16x32_bf16(pa, bv, oa[n16], 0, 0, 0);
      }
    }
    #pragma unroll
    for (int n16 = 0; n16 < 2; n16++)
      #pragma unroll
      for (int rg = 0; rg < 4; rg++){
        int q = w*64 + qg*16 + quad*4 + rg;
        int col = hh*32 + n16*16 + l15;
        obb[((size_t)(g<<8) + q)*128 + col] = f2b(oa[n16][rg] * inv_l[rg]);
      }
  }
}

// ============================================================
// mean-pool + 2-layer head
// ============================================================
__global__ __launch_bounds__(256) void head_kernel(const ushort* __restrict__ hb,
                                                   const float* __restrict__ W1, const float* __restrict__ b1,
                                                   const float* __restrict__ W2, const float* __restrict__ b2,
                                                   float* __restrict__ out){
  int g = blockIdx.x, tid = threadIdx.x;
  int c = tid & 127, half = tid >> 7;
  __shared__ float part[2][128];
  __shared__ float pool[128];
  __shared__ float hid[64];
  float s = 0.f;
  for (int n = half*128; n < half*128 + 128; n++)
    s += b2f(hb[(size_t)((g<<8)+n)*128 + c]);
  part[half][c] = s;
  __syncthreads();
  if (tid < 128) pool[tid] = (part[0][tid] + part[1][tid]) * (1.f/256.f);
  __syncthreads();
  if (tid < 64){
    float v = b1[tid];
    for (int k = 0; k < 128; k++) v += pool[k] * W1[k*64 + tid];
    hid[tid] = fmaxf(v, 0.f);
  }
  __syncthreads();
  if (tid == 0){
    float v = b2[0];
    for (int k = 0; k < 64; k++) v += hid[k] * W2[k];
    out[g] = v;
  }
}

// ============================================================
extern "C" void kernel_launch(void* const* d_in, const int* in_sizes, int n_in,
                              void* d_out, int out_size, void* d_ws, size_t ws_size,
                              hipStream_t stream){
  (void)in_sizes; (void)n_in; (void)out_size; (void)ws_size;
  const float* x      = (const float*)d_in[0];
  const float* eattr  = (const float*)d_in[1];
  const float* in_W   = (const float*)d_in[2];
  const float* in_b   = (const float*)d_in[3];
  const float* ep_W   = (const float*)d_in[4];
  const float* ep_b   = (const float*)d_in[5];
  const float* ge_W   = (const float*)d_in[6];
  const float* ge_b   = (const float*)d_in[7];
  const float* g1_W   = (const float*)d_in[8];
  const float* g1_b   = (const float*)d_in[9];
  const float* g2_W   = (const float*)d_in[10];
  const float* g2_b   = (const float*)d_in[11];
  const float* qkv_W  = (const float*)d_in[12];
  const float* qkv_b  = (const float*)d_in[13];
  const float* o_W    = (const float*)d_in[14];
  const float* o_b    = (const float*)d_in[15];
  const float* bn1g = (const float*)d_in[16]; const float* bn1b = (const float*)d_in[17];
  const float* bn1m = (const float*)d_in[18]; const float* bn1v = (const float*)d_in[19];
  const float* bn2g = (const float*)d_in[20]; const float* bn2b = (const float*)d_in[21];
  const float* bn2m = (const float*)d_in[22]; const float* bn2v = (const float*)d_in[23];
  const float* bn3g = (const float*)d_in[24]; const float* bn3b = (const float*)d_in[25];
  const float* bn3m = (const float*)d_in[26]; const float* bn3v = (const float*)d_in[27];
  const float* m1_W = (const float*)d_in[28]; const float* m1_b = (const float*)d_in[29];
  const float* m2_W = (const float*)d_in[30]; const float* m2_b = (const float*)d_in[31];
  const float* h1_W = (const float*)d_in[32]; const float* h1_b = (const float*)d_in[33];
  const float* h2_W = (const float*)d_in[34]; const float* h2_b = (const float*)d_in[35];
  const int*   ei   = (const int*)d_in[36];
  float* out = (float*)d_out;
  float* ws  = (float*)d_ws;
  int*   wsi = (int*)d_ws;

  // ---- workspace layout (fp32-element offsets) ----
  const size_t oA    = 0;            // 8,388,608  (dead after prep_m)
  const size_t oMbf  = 8388608;      // 4,194,304  (dead after rwse_mf)
  // overlays of [0, 12.58M): xinb (1.05M), then qkvb (6.29M)
  const size_t oPk   = 12582912;     // 12,582,912
  const size_t oDeg  = 25165824;     // 32,768
  const size_t oPe   = 25198592;     // 655,360
  const size_t oHb   = 25853952;     // 2,097,152 (bf16 h)
  const size_t oH1b  = 27951104;     // 2,097,152 (bf16 h1)
  const size_t oBb   = 30048256;     // 2,097,152 (bf16 aggr / attn-out, shared)
  const size_t oWp   = 32145408;     // 4,224
  const size_t oBp   = 32149632;     // 384
  const size_t oEpos = 32150016;     // 262,144
  const size_t oEcnt = 32412160;     // 32,768
  const size_t oWT   = 32444928;     // 499,712 ushort
  ushort* wt   = (ushort*)(ws + oWT);
  ushort* mbf  = (ushort*)(ws + oMbf);
  ushort* xinb = (ushort*)(ws + 0);
  ushort* qkvb = (ushort*)(ws + 0);
  ushort* hb   = (ushort*)(ws + oHb);
  ushort* h1b  = (ushort*)(ws + oH1b);
  ushort* bbuf = (ushort*)(ws + oBb);

  // ---- build + RWSE ----
  hipMemsetAsync(ws + oA, 0, 8388608*sizeof(float), stream);
  hipMemsetAsync(wsi + oEcnt, 0, 32768*sizeof(int), stream);
  build_edges<<<NEDGE/256, 256, 0, stream>>>(ei, ws+oA, wsi+oEpos, wsi+oEcnt);
  pack_edges<<<NEDGE/256, 256, 0, stream>>>(ei, eattr, wsi+oEpos, ws+oPk);
  rwse_deg<<<GN, 256, 0, stream>>>(ws+oA, ws+oDeg);
  prep_m<<<GN, 256, 0, stream>>>(ws+oA, ws+oDeg, mbf);
  rwse_mf<<<GN*4, 256, 0, stream>>>(mbf, ws+oPe);

  // ---- weight prep ----
  prep_wt<<<dim3(192, 19), 256, 0, stream>>>(in_W, g1_W, g2_W, qkv_W, o_W, m1_W, m2_W, wt);

  // ---- input proj ----
  concat_kernel<<<NN*64/256, 256, 0, stream>>>(x, ws+oPe, xinb);
  gemm_b<64><<<512, 256, 0, stream>>>(xinb, wt + 0, in_b, hb, 128, 1);

  wp_all<<<3, 256, 0, stream>>>(ep_W, ep_b, ge_W, ge_b, ws+oWp, ws+oBp);

  // ---- layers ----
  for (int i = 0; i < 3; i++){
    gine_aggr2<<<NN/2, 256, 0, stream>>>(hb, ws+oPk, wsi+oEcnt,
                                         ws+oWp + (size_t)i*1408, ws+oBp + (size_t)i*128, bbuf);
    gine_mlp<<<512, 256, 0, stream>>>(hb, bbuf,
        wt + 8192 + (size_t)i*16384, g1_b + (size_t)i*128,
        wt + 57344 + (size_t)i*16384, g2_b + (size_t)i*128,
        bn1g+(size_t)i*128, bn1b+(size_t)i*128, bn1m+(size_t)i*128, bn1v+(size_t)i*128,
        h1b);
    gemm_b<128><<<1536, 256, 0, stream>>>(hb, wt + 106496 + (size_t)i*49152,
                                          qkv_b + (size_t)i*384, qkvb, 384, 3);
    attn_mf<<<GN*4, 256, 0, stream>>>(qkvb, bbuf);
    ff_fused<<<512, 256, 0, stream>>>(bbuf, hb, h1b,
        wt + 253952 + (size_t)i*16384, o_b + (size_t)i*128,
        bn2g+(size_t)i*128, bn2b+(size_t)i*128, bn2m+(size_t)i*128, bn2v+(size_t)i*128,
        wt + 303104 + (size_t)i*32768, m1_b + (size_t)i*256,
        wt + 401408 + (size_t)i*32768, m2_b + (size_t)i*128,
        bn3g+(size_t)i*128, bn3b+(size_t)i*128, bn3m+(size_t)i*128, bn3v+(size_t)i*128,
        hb);
  }

  head_kernel<<<GN, 256, 0, stream>>>(hb, h1_W, h1_b, h2_W, h2_b, out);
}